// Round 1
// baseline (585.388 us; speedup 1.0000x reference)
//
#include <hip/hip_runtime.h>
#include <math.h>

// Problem dims (fixed)
#define TT 4
#define BB 8
#define CC 384
#define HWN 1024      // 32*32
#define NHEAD 12
#define CHD 32        // C / heads
#define C2 768        // 2*C
#define LL 64         // 8*8 patches
#define KCONV 6144    // C*4*4

// ---------------- K0: transpose w_conv [768][6144] -> wT [6144][768] ----------------
__global__ __launch_bounds__(256) void k_transpose_wconv(const float* __restrict__ w,
                                                         float* __restrict__ wT) {
    __shared__ float tile[32][33];
    int k0 = blockIdx.x * 32;   // 0..6143
    int oc0 = blockIdx.y * 32;  // 0..767
    int lk = threadIdx.x & 31;
    int lo = threadIdx.x >> 5;  // 0..7
#pragma unroll
    for (int i = 0; i < 4; i++) {
        int oc = lo + i * 8;
        tile[oc][lk] = w[(size_t)(oc0 + oc) * KCONV + k0 + lk];
    }
    __syncthreads();
#pragma unroll
    for (int i = 0; i < 4; i++) {
        int k = lo + i * 8;
        wT[(size_t)(k0 + k) * C2 + oc0 + lk] = tile[lk][k];
    }
}

// ---------------- K1: LIF over T on x -> spikes u8 ----------------
__global__ __launch_bounds__(256) void k_lif1(const float* __restrict__ x,
                                              unsigned char* __restrict__ xs) {
    const int stride = BB * CC * HWN;  // 3,145,728
    int idx = blockIdx.x * 256 + threadIdx.x;
    float v = 0.0f;
#pragma unroll
    for (int t = 0; t < TT; t++) {
        float xv = x[(size_t)t * stride + idx];
        v += (xv - v) * 0.5f;
        unsigned char s = (v >= 1.0f) ? 1 : 0;
        xs[(size_t)t * stride + idx] = s;
        if (s) v = 0.0f;
    }
}

// ---------------- K2: conv-as-GEMM + BN1 -> y [T,B,768,64] ----------------
// grid: 192 blocks = 32 (t,b) * 6 oc-tiles(128). block 256.
// tile: 64 pp x 128 oc, reg tile 4x8 per thread.
__global__ __launch_bounds__(256) void k_conv_bn(const unsigned char* __restrict__ xs,
                                                 const float* __restrict__ wT,
                                                 const float* __restrict__ g1,
                                                 const float* __restrict__ b1,
                                                 const float* __restrict__ m1,
                                                 const float* __restrict__ v1,
                                                 float* __restrict__ y) {
    __shared__ float A_sf[32][68];   // [k][pp]
    __shared__ float B_s[32][132];   // [k][oc]
    int bid = blockIdx.x;
    int tb = bid / 6;
    int oc0 = (bid % 6) * 128;
    const unsigned char* xsb = xs + (size_t)tb * CC * HWN;
    int tid = threadIdx.x;
    int tx = tid & 15, ty = tid >> 4;
    int pp_l = tx * 4, oc_l = ty * 8;
    float acc[4][8];
#pragma unroll
    for (int i = 0; i < 4; i++)
#pragma unroll
        for (int j = 0; j < 8; j++) acc[i][j] = 0.0f;

    for (int kc = 0; kc < KCONV; kc += 32) {
        __syncthreads();
        // stage A (binary spikes -> f32), k = c*16 + a*4 + b
#pragma unroll
        for (int i = 0; i < 2; i++) {
            int idx = tid + i * 256;        // 0..511
            int pp = idx & 63;
            int kk4 = idx >> 6;             // 0..7
            int kg = kc + kk4 * 4;
            int c = kg >> 4;
            int a = (kg & 15) >> 2;
            int pi = pp >> 3, pj = pp & 7;
            uchar4 v = *(const uchar4*)(xsb + (size_t)c * HWN + (pi * 4 + a) * 32 + pj * 4);
            A_sf[kk4 * 4 + 0][pp] = (float)v.x;
            A_sf[kk4 * 4 + 1][pp] = (float)v.y;
            A_sf[kk4 * 4 + 2][pp] = (float)v.z;
            A_sf[kk4 * 4 + 3][pp] = (float)v.w;
        }
        // stage B from wT (coalesced float4)
#pragma unroll
        for (int i = 0; i < 4; i++) {
            int idx = tid + i * 256;        // 0..1023
            int kk = idx >> 5;
            int oc4 = (idx & 31) * 4;
            float4 v = *(const float4*)(wT + (size_t)(kc + kk) * C2 + oc0 + oc4);
            *(float4*)&B_s[kk][oc4] = v;
        }
        __syncthreads();
#pragma unroll
        for (int kk = 0; kk < 32; kk++) {
            float4 a4 = *(const float4*)&A_sf[kk][pp_l];
            float4 bq0 = *(const float4*)&B_s[kk][oc_l];
            float4 bq1 = *(const float4*)&B_s[kk][oc_l + 4];
            float av[4] = {a4.x, a4.y, a4.z, a4.w};
            float bv[8] = {bq0.x, bq0.y, bq0.z, bq0.w, bq1.x, bq1.y, bq1.z, bq1.w};
#pragma unroll
            for (int ii = 0; ii < 4; ii++)
#pragma unroll
                for (int jj = 0; jj < 8; jj++)
                    acc[ii][jj] = fmaf(av[ii], bv[jj], acc[ii][jj]);
        }
    }
    // epilogue: BN1, store y[t,b,oc,pp]
    size_t ybase = (size_t)tb * C2 * LL;
#pragma unroll
    for (int j = 0; j < 8; j++) {
        int oc = oc0 + oc_l + j;
        float inv = g1[oc] / sqrtf(v1[oc] + 1e-5f);
        float mu = m1[oc];
        float bt = b1[oc];
        float4 o;
        o.x = (acc[0][j] - mu) * inv + bt;
        o.y = (acc[1][j] - mu) * inv + bt;
        o.z = (acc[2][j] - mu) * inv + bt;
        o.w = (acc[3][j] - mu) * inv + bt;
        *(float4*)(y + ybase + (size_t)oc * LL + pp_l) = o;
    }
}

// ---------------- K3: fused attention (einsum1 -> LIF -> einsum2 -> LIF) -> os u8 ----------------
// grid: (8 n-tiles of 128, 96 = B*heads). block 256.
__global__ __launch_bounds__(256) void k_attn(const unsigned char* __restrict__ xs,
                                              const float* __restrict__ y,
                                              const float* __restrict__ fr_x,
                                              const float* __restrict__ fr_attn,
                                              unsigned char* __restrict__ os) {
    __shared__ float y1s[32][68];    // [d][p]
    __shared__ float y2s[32][68];    // [d][p]
    __shared__ float xrs[32][132];   // [d][nn]
    __shared__ float sat[64][132];   // [p][nn] attn spikes

    int n0 = blockIdx.x * 128;
    int bh = blockIdx.y;
    int b = bh / NHEAD, hh = bh % NHEAD;
    int tid = threadIdx.x;
    int tx = tid & 15, ty = tid >> 4;
    int nn_l = tx * 8;
    int p_l = ty * 4;   // phase A
    int d_l = ty * 2;   // phase B

    float scale1 = 1.0f / sqrtf(fr_x[hh] * 32.0f);
    float scale2 = 1.0f / sqrtf(fr_attn[hh] * 64.0f);

    float va[4][8];   // attn LIF state
    float vo[2][8];   // out LIF state
#pragma unroll
    for (int i = 0; i < 4; i++)
#pragma unroll
        for (int j = 0; j < 8; j++) va[i][j] = 0.0f;
#pragma unroll
    for (int i = 0; i < 2; i++)
#pragma unroll
        for (int j = 0; j < 8; j++) vo[i][j] = 0.0f;

    for (int t = 0; t < TT; t++) {
        __syncthreads();
        int tb = t * BB + b;
        const float* y1g = y + ((size_t)tb * C2 + hh * 64) * LL;
        const float* y2g = y1g + 32 * LL;
#pragma unroll
        for (int i = 0; i < 2; i++) {
            int f4 = tid + i * 256;        // 0..511 ; 16 float4 per row
            int d = f4 >> 4, pq = (f4 & 15) * 4;
            *(float4*)&y1s[d][pq] = *(const float4*)(y1g + d * LL + pq);
            *(float4*)&y2s[d][pq] = *(const float4*)(y2g + d * LL + pq);
        }
        const unsigned char* xg = xs + ((size_t)tb * CC + hh * CHD) * HWN + n0;
#pragma unroll
        for (int i = 0; i < 4; i++) {
            int u4 = tid + i * 256;        // 0..1023 ; 32 uchar4 per row
            int d = u4 >> 5, nb = (u4 & 31) * 4;
            uchar4 v = *(const uchar4*)(xg + (size_t)d * HWN + nb);
            xrs[d][nb + 0] = (float)v.x;
            xrs[d][nb + 1] = (float)v.y;
            xrs[d][nb + 2] = (float)v.z;
            xrs[d][nb + 3] = (float)v.w;
        }
        __syncthreads();

        // phase A: attn_raw[p][nn] = sum_d y1[d][p] * xr[d][nn]
        float acca[4][8];
#pragma unroll
        for (int i = 0; i < 4; i++)
#pragma unroll
            for (int j = 0; j < 8; j++) acca[i][j] = 0.0f;
        for (int d = 0; d < 32; d++) {
            float4 a4 = *(const float4*)&y1s[d][p_l];
            float4 x0 = *(const float4*)&xrs[d][nn_l];
            float4 x1 = *(const float4*)&xrs[d][nn_l + 4];
            float av[4] = {a4.x, a4.y, a4.z, a4.w};
            float xv[8] = {x0.x, x0.y, x0.z, x0.w, x1.x, x1.y, x1.z, x1.w};
#pragma unroll
            for (int ii = 0; ii < 4; ii++)
#pragma unroll
                for (int jj = 0; jj < 8; jj++)
                    acca[ii][jj] = fmaf(av[ii], xv[jj], acca[ii][jj]);
        }
        // attn LIF -> spikes to LDS
#pragma unroll
        for (int ii = 0; ii < 4; ii++)
#pragma unroll
            for (int jj = 0; jj < 8; jj++) {
                float a = acca[ii][jj] * scale1;
                float v = va[ii][jj];
                v += (a - v) * 0.5f;
                float s = (v >= 1.0f) ? 1.0f : 0.0f;
                va[ii][jj] = (s > 0.0f) ? 0.0f : v;
                sat[p_l + ii][nn_l + jj] = s;
            }
        __syncthreads();

        // phase B: out_raw[d][nn] = sum_p y2[d][p] * sat[p][nn]
        float acco[2][8];
#pragma unroll
        for (int i = 0; i < 2; i++)
#pragma unroll
            for (int j = 0; j < 8; j++) acco[i][j] = 0.0f;
        for (int p = 0; p < 64; p++) {
            float4 s0 = *(const float4*)&sat[p][nn_l];
            float4 s1 = *(const float4*)&sat[p][nn_l + 4];
            float sv[8] = {s0.x, s0.y, s0.z, s0.w, s1.x, s1.y, s1.z, s1.w};
            float w0 = y2s[d_l][p];
            float w1 = y2s[d_l + 1][p];
#pragma unroll
            for (int jj = 0; jj < 8; jj++) {
                acco[0][jj] = fmaf(w0, sv[jj], acco[0][jj]);
                acco[1][jj] = fmaf(w1, sv[jj], acco[1][jj]);
            }
        }
        // out LIF -> spikes to global (u8)
        unsigned char* og = os + ((size_t)tb * CC + hh * CHD) * HWN + n0;
#pragma unroll
        for (int di = 0; di < 2; di++)
#pragma unroll
            for (int jj = 0; jj < 8; jj++) {
                float a = acco[di][jj] * scale2;
                float v = vo[di][jj];
                v += (a - v) * 0.5f;
                float s = (v >= 1.0f) ? 1.0f : 0.0f;
                vo[di][jj] = (s > 0.0f) ? 0.0f : v;
                og[(size_t)(d_l + di) * HWN + nn_l + jj] = (unsigned char)s;
            }
    }
}

// ---------------- K4: projection GEMM + BN2 + residual -> d_out ----------------
// grid: 1536 = 32 (t,b) * 6 o-tiles(64) * 8 hw-tiles(128). block 256.
__global__ __launch_bounds__(256) void k_proj(const unsigned char* __restrict__ os,
                                              const float* __restrict__ wp,
                                              const float* __restrict__ g2,
                                              const float* __restrict__ b2,
                                              const float* __restrict__ m2,
                                              const float* __restrict__ vv2,
                                              const float* __restrict__ x,
                                              float* __restrict__ out) {
    __shared__ float wps[32][68];   // [k][o]
    __shared__ float ss[32][132];   // [k][hw]
    int bid = blockIdx.x;
    int tb = bid / 48;
    int rem = bid % 48;
    int o0 = (rem / 8) * 64;
    int n0 = (rem % 8) * 128;
    int tid = threadIdx.x;
    int tx = tid & 15, ty = tid >> 4;
    int hw_l = tx * 8, o_l = ty * 4;
    float acc[4][8];
#pragma unroll
    for (int i = 0; i < 4; i++)
#pragma unroll
        for (int j = 0; j < 8; j++) acc[i][j] = 0.0f;

    for (int kc = 0; kc < CC; kc += 32) {
        __syncthreads();
        // stage wp tile, transposed to [k][o]
#pragma unroll
        for (int i = 0; i < 2; i++) {
            int f4 = tid + i * 256;        // 0..511 ; 8 float4 per o-row
            int o = f4 >> 3, cb = (f4 & 7) * 4;
            float4 v = *(const float4*)(wp + (size_t)(o0 + o) * CC + kc + cb);
            wps[cb + 0][o] = v.x;
            wps[cb + 1][o] = v.y;
            wps[cb + 2][o] = v.z;
            wps[cb + 3][o] = v.w;
        }
        // stage spikes
#pragma unroll
        for (int i = 0; i < 4; i++) {
            int u4 = tid + i * 256;
            int kk = u4 >> 5, nb = (u4 & 31) * 4;
            uchar4 v = *(const uchar4*)(os + ((size_t)tb * CC + kc + kk) * HWN + n0 + nb);
            ss[kk][nb + 0] = (float)v.x;
            ss[kk][nb + 1] = (float)v.y;
            ss[kk][nb + 2] = (float)v.z;
            ss[kk][nb + 3] = (float)v.w;
        }
        __syncthreads();
#pragma unroll
        for (int kk = 0; kk < 32; kk++) {
            float4 a4 = *(const float4*)&wps[kk][o_l];
            float4 s0 = *(const float4*)&ss[kk][hw_l];
            float4 s1 = *(const float4*)&ss[kk][hw_l + 4];
            float av[4] = {a4.x, a4.y, a4.z, a4.w};
            float sv[8] = {s0.x, s0.y, s0.z, s0.w, s1.x, s1.y, s1.z, s1.w};
#pragma unroll
            for (int ii = 0; ii < 4; ii++)
#pragma unroll
                for (int jj = 0; jj < 8; jj++)
                    acc[ii][jj] = fmaf(av[ii], sv[jj], acc[ii][jj]);
        }
    }
    // epilogue: BN2 + residual
#pragma unroll
    for (int oi = 0; oi < 4; oi++) {
        int o = o0 + o_l + oi;
        float inv = g2[o] / sqrtf(vv2[o] + 1e-5f);
        float mu = m2[o];
        float bt = b2[o];
        size_t base = ((size_t)tb * CC + o) * HWN + n0 + hw_l;
        float4 xv0 = *(const float4*)(x + base);
        float4 xv1 = *(const float4*)(x + base + 4);
        float4 o0v, o1v;
        o0v.x = (acc[oi][0] - mu) * inv + bt + xv0.x;
        o0v.y = (acc[oi][1] - mu) * inv + bt + xv0.y;
        o0v.z = (acc[oi][2] - mu) * inv + bt + xv0.z;
        o0v.w = (acc[oi][3] - mu) * inv + bt + xv0.w;
        o1v.x = (acc[oi][4] - mu) * inv + bt + xv1.x;
        o1v.y = (acc[oi][5] - mu) * inv + bt + xv1.y;
        o1v.z = (acc[oi][6] - mu) * inv + bt + xv1.z;
        o1v.w = (acc[oi][7] - mu) * inv + bt + xv1.w;
        *(float4*)(out + base) = o0v;
        *(float4*)(out + base + 4) = o1v;
    }
}

extern "C" void kernel_launch(void* const* d_in, const int* in_sizes, int n_in,
                              void* d_out, int out_size, void* d_ws, size_t ws_size,
                              hipStream_t stream) {
    const float* x = (const float*)d_in[0];
    const float* w_conv = (const float*)d_in[1];
    const float* bn1_gamma = (const float*)d_in[2];
    const float* bn1_beta = (const float*)d_in[3];
    const float* bn1_mean = (const float*)d_in[4];
    const float* bn1_var = (const float*)d_in[5];
    const float* w_proj = (const float*)d_in[6];
    const float* bn2_gamma = (const float*)d_in[7];
    const float* bn2_beta = (const float*)d_in[8];
    const float* bn2_mean = (const float*)d_in[9];
    const float* bn2_var = (const float*)d_in[10];
    const float* fr_x = (const float*)d_in[11];
    const float* fr_attn = (const float*)d_in[12];

    // workspace layout
    const size_t SPIKE_BYTES = (size_t)TT * BB * CC * HWN;  // 12,582,912
    unsigned char* xs = (unsigned char*)d_ws;
    unsigned char* os = xs + SPIKE_BYTES;
    float* y = (float*)(os + SPIKE_BYTES);                  // 6,291,456 B
    float* wT = y + (size_t)TT * BB * C2 * LL;              // 18,874,368 B

    // K0: transpose conv weights
    k_transpose_wconv<<<dim3(KCONV / 32, C2 / 32), 256, 0, stream>>>(w_conv, wT);
    // K1: LIF on x
    k_lif1<<<(BB * CC * HWN) / 256, 256, 0, stream>>>(x, xs);
    // K2: conv + BN1
    k_conv_bn<<<32 * 6, 256, 0, stream>>>(xs, wT, bn1_gamma, bn1_beta, bn1_mean, bn1_var, y);
    // K3: fused attention
    k_attn<<<dim3(8, BB * NHEAD), 256, 0, stream>>>(xs, y, fr_x, fr_attn, os);
    // K4: projection + BN2 + residual
    k_proj<<<32 * 6 * 8, 256, 0, stream>>>(os, w_proj, bn2_gamma, bn2_beta, bn2_mean, bn2_var, x, (float*)d_out);
}

// Round 2
// 311.614 us; speedup vs baseline: 1.8786x; 1.8786x over previous
//
#include <hip/hip_runtime.h>
#include <math.h>

// Problem dims (fixed)
#define TT 4
#define BB 8
#define CC 384
#define HWN 1024      // 32*32
#define NHEAD 12
#define CHD 32        // C / heads
#define C2 768        // 2*C
#define LL 64         // 8*8 patches
#define KCONV 6144    // C*4*4
#define KB_TOT 192    // KCONV/32
#define MROWS 2048    // TT*BB*64

typedef _Float16 f16x8 __attribute__((ext_vector_type(8)));
typedef _Float16 f16x4 __attribute__((ext_vector_type(4)));
typedef float f32x4 __attribute__((ext_vector_type(4)));

#if defined(__has_builtin)
#if __has_builtin(__builtin_amdgcn_global_load_lds)
#define USE_GLL 1
#endif
#endif
#ifndef USE_GLL
#define USE_GLL 0
#endif

#if USE_GLL
typedef __attribute__((address_space(3))) unsigned int lds_uint;
typedef const __attribute__((address_space(1))) unsigned int glob_uint;
__device__ __forceinline__ void load_lds16(const void* g, void* l) {
    __builtin_amdgcn_global_load_lds((glob_uint*)g, (lds_uint*)l, 16, 0, 0);
}
#endif

// ---------------- K0: pack w_conv into fragment-major f16 hi/lo splits ----------------
// Layout: W[(kb*6+nb)*4096 + q*1024 + col*8 + j], k = kb*32 + q*8 + j, n = nb*128+col.
__global__ __launch_bounds__(256) void k_pack(const float* __restrict__ w,
                                              _Float16* __restrict__ W0,
                                              _Float16* __restrict__ W1) {
    int g = blockIdx.x * 256 + threadIdx.x;   // 0..589823
    int o = g * 8;
    int kbnb = o >> 12;                        // kb*6+nb
    int kb = kbnb / 6;
    int nb = kbnb - kb * 6;
    int q = (o >> 10) & 3;
    int col = (o >> 3) & 127;
    int k = kb * 32 + q * 8;
    int n = nb * 128 + col;
    const float* src = w + (size_t)n * KCONV + k;
    f16x8 h, l;
#pragma unroll
    for (int j = 0; j < 8; j++) {
        float wv = src[j];
        _Float16 hi = (_Float16)wv;
        float rem = (wv - (float)hi) * 2048.0f;
        h[j] = hi;
        l[j] = (_Float16)rem;
    }
    *(f16x8*)(W0 + o) = h;
    *(f16x8*)(W1 + o) = l;
}

// ---------------- K1: LIF over T on x -> spikes u8 ----------------
__global__ __launch_bounds__(256) void k_lif1(const float* __restrict__ x,
                                              unsigned char* __restrict__ xs) {
    const int stride = BB * CC * HWN;
    int idx = blockIdx.x * 256 + threadIdx.x;
    float v = 0.0f;
#pragma unroll
    for (int t = 0; t < TT; t++) {
        float xv = x[(size_t)t * stride + idx];
        v += (xv - v) * 0.5f;
        unsigned char s = (v >= 1.0f) ? 1 : 0;
        xs[(size_t)t * stride + idx] = s;
        if (s) v = 0.0f;
    }
}

// ---------------- K2: conv-as-GEMM via f16 MFMA (hi/lo split), split-K partials ----------------
// grid (16 mtiles, 6 ntiles, KS). block 256 = 4 waves, each wave 64x64.
__global__ __launch_bounds__(256) void k_conv_mfma(const unsigned char* __restrict__ xs,
                                                   const _Float16* __restrict__ W0,
                                                   const _Float16* __restrict__ W1,
                                                   float* __restrict__ P,
                                                   int kbPerSplit) {
    __shared__ __align__(16) _Float16 Asmem[4][128][8];       // 8 KB   [q][row][j]
    __shared__ __align__(16) _Float16 Bsmem[2][4][128][8];    // 16 KB  [split][q][col][j]

    int mt = blockIdx.x;
    int nt = blockIdx.y;
    int s = blockIdx.z;
    int kb0 = s * kbPerSplit;
    int tid = threadIdx.x;
    int wave = tid >> 6;
    int lane = tid & 63;
    int l16 = lane & 15, lq = lane >> 4;
    int wr = (wave & 1) * 64, wc = (wave >> 1) * 64;

    f32x4 acc0[4][4], acc1[4][4];
#pragma unroll
    for (int i = 0; i < 4; i++)
#pragma unroll
        for (int j = 0; j < 4; j++) {
            acc0[i][j] = (f32x4){0.f, 0.f, 0.f, 0.f};
            acc1[i][j] = (f32x4){0.f, 0.f, 0.f, 0.f};
        }

    // A-gather setup: thread handles one row, one channel-half (16 k's)
    int row = tid & 127;
    int hf = tid >> 7;                 // 0/1
    int m = mt * 128 + row;
    int tb = m >> 6, pp = m & 63;
    int pi = pp >> 3, pj = pp & 7;
    const unsigned char* xsb = xs + (size_t)tb * (CC * HWN) + (pi * 4) * 32 + pj * 4;

    for (int kb = kb0; kb < kb0 + kbPerSplit; ++kb) {
        __syncthreads();
        // stage A: channel = kb*2 + hf, k32 = hf*16 + a*4 + b
        const unsigned char* src = xsb + (size_t)(kb * 2 + hf) * HWN;
#pragma unroll
        for (int a = 0; a < 4; ++a) {
            uchar4 u = *(const uchar4*)(src + a * 32);
            f16x4 hv;
            hv[0] = (_Float16)u.x;
            hv[1] = (_Float16)u.y;
            hv[2] = (_Float16)u.z;
            hv[3] = (_Float16)u.w;
            *(f16x4*)&Asmem[2 * hf + (a >> 1)][row][(a & 1) * 4] = hv;
        }
        // stage B: 16 KB linear copy from packed weights
        const char* wb0 = (const char*)W0 + (size_t)(kb * 6 + nt) * 8192;
        const char* wb1 = (const char*)W1 + (size_t)(kb * 6 + nt) * 8192;
#if USE_GLL
#pragma unroll
        for (int i = 0; i < 4; ++i) {
            int off = (wave * 4 + i) * 1024;
            const char* wb = (off & 8192) ? wb1 : wb0;
            load_lds16(wb + (off & 8191) + lane * 16, (char*)&Bsmem[0][0][0][0] + off);
        }
#else
#pragma unroll
        for (int i = 0; i < 4; ++i) {
            int off = (tid + i * 256) * 16;
            const char* wb = (off & 8192) ? wb1 : wb0;
            *(float4*)((char*)&Bsmem[0][0][0][0] + off) = *(const float4*)(wb + (off & 8191));
        }
#endif
        __syncthreads();

        f16x8 af[4], bf0[4], bf1[4];
#pragma unroll
        for (int fi = 0; fi < 4; fi++) af[fi] = *(const f16x8*)&Asmem[lq][wr + fi * 16 + l16][0];
#pragma unroll
        for (int fj = 0; fj < 4; fj++) {
            bf0[fj] = *(const f16x8*)&Bsmem[0][lq][wc + fj * 16 + l16][0];
            bf1[fj] = *(const f16x8*)&Bsmem[1][lq][wc + fj * 16 + l16][0];
        }
#pragma unroll
        for (int fi = 0; fi < 4; fi++)
#pragma unroll
            for (int fj = 0; fj < 4; fj++) {
                acc0[fi][fj] = __builtin_amdgcn_mfma_f32_16x16x32_f16(af[fi], bf0[fj], acc0[fi][fj], 0, 0, 0);
                acc1[fi][fj] = __builtin_amdgcn_mfma_f32_16x16x32_f16(af[fi], bf1[fj], acc1[fi][fj], 0, 0, 0);
            }
    }

    // epilogue: combine splits, store partial
    size_t Pbase = (size_t)s * MROWS * C2;
#pragma unroll
    for (int fi = 0; fi < 4; fi++)
#pragma unroll
        for (int fj = 0; fj < 4; fj++) {
            int ccol = nt * 128 + wc + fj * 16 + l16;
#pragma unroll
            for (int r = 0; r < 4; r++) {
                int rr = mt * 128 + wr + fi * 16 + lq * 4 + r;
                float v = acc0[fi][fj][r] + acc1[fi][fj][r] * (1.0f / 2048.0f);
                P[Pbase + (size_t)rr * C2 + ccol] = v;
            }
        }
}

// ---------------- K2b: reduce split-K partials + BN1 -> y_t [tb][pp][oc] ----------------
__global__ __launch_bounds__(256) void k_reduce_bn(const float* __restrict__ P,
                                                   const float* __restrict__ g1,
                                                   const float* __restrict__ b1,
                                                   const float* __restrict__ m1,
                                                   const float* __restrict__ v1,
                                                   float* __restrict__ y_t,
                                                   int KS) {
    int e = blockIdx.x * 256 + threadIdx.x;   // 0..1572863
    float sum = 0.0f;
    for (int s = 0; s < KS; s++) sum += P[(size_t)s * MROWS * C2 + e];
    int n = e % C2;
    float inv = g1[n] / sqrtf(v1[n] + 1e-5f);
    y_t[e] = (sum - m1[n]) * inv + b1[n];
}

// ---------------- K3: fused attention -> os u8 ----------------
__global__ __launch_bounds__(256) void k_attn(const unsigned char* __restrict__ xs,
                                              const float* __restrict__ y_t,
                                              const float* __restrict__ fr_x,
                                              const float* __restrict__ fr_attn,
                                              unsigned char* __restrict__ os) {
    __shared__ float y1s[32][68];
    __shared__ float y2s[32][68];
    __shared__ float xrs[32][132];
    __shared__ float sat[64][132];

    int n0 = blockIdx.x * 128;
    int bh = blockIdx.y;
    int b = bh / NHEAD, hh = bh % NHEAD;
    int tid = threadIdx.x;
    int tx = tid & 15, ty = tid >> 4;
    int nn_l = tx * 8;
    int p_l = ty * 4;
    int d_l = ty * 2;

    float scale1 = 1.0f / sqrtf(fr_x[hh] * 32.0f);
    float scale2 = 1.0f / sqrtf(fr_attn[hh] * 64.0f);

    float va[4][8];
    float vo[2][8];
#pragma unroll
    for (int i = 0; i < 4; i++)
#pragma unroll
        for (int j = 0; j < 8; j++) va[i][j] = 0.0f;
#pragma unroll
    for (int i = 0; i < 2; i++)
#pragma unroll
        for (int j = 0; j < 8; j++) vo[i][j] = 0.0f;

    for (int t = 0; t < TT; t++) {
        __syncthreads();
        int tb = t * BB + b;
        // y_t layout: [tb][p=64][oc=768]; (d,p) at p*768 + hh*64 + d
        const float* yg = y_t + (size_t)tb * (LL * C2) + hh * 64;
#pragma unroll
        for (int i = 0; i < 16; i++) {
            int f = i * 256 + tid;    // 0..4095
            int p = f >> 6, dc = f & 63;
            float v = yg[(size_t)p * C2 + dc];
            if (dc < 32) y1s[dc][p] = v;
            else y2s[dc - 32][p] = v;
        }
        const unsigned char* xg = xs + ((size_t)tb * CC + hh * CHD) * HWN + n0;
#pragma unroll
        for (int i = 0; i < 4; i++) {
            int u4 = tid + i * 256;
            int d = u4 >> 5, nb = (u4 & 31) * 4;
            uchar4 v = *(const uchar4*)(xg + (size_t)d * HWN + nb);
            xrs[d][nb + 0] = (float)v.x;
            xrs[d][nb + 1] = (float)v.y;
            xrs[d][nb + 2] = (float)v.z;
            xrs[d][nb + 3] = (float)v.w;
        }
        __syncthreads();

        float acca[4][8];
#pragma unroll
        for (int i = 0; i < 4; i++)
#pragma unroll
            for (int j = 0; j < 8; j++) acca[i][j] = 0.0f;
        for (int d = 0; d < 32; d++) {
            float4 a4 = *(const float4*)&y1s[d][p_l];
            float4 x0 = *(const float4*)&xrs[d][nn_l];
            float4 x1 = *(const float4*)&xrs[d][nn_l + 4];
            float av[4] = {a4.x, a4.y, a4.z, a4.w};
            float xv[8] = {x0.x, x0.y, x0.z, x0.w, x1.x, x1.y, x1.z, x1.w};
#pragma unroll
            for (int ii = 0; ii < 4; ii++)
#pragma unroll
                for (int jj = 0; jj < 8; jj++)
                    acca[ii][jj] = fmaf(av[ii], xv[jj], acca[ii][jj]);
        }
#pragma unroll
        for (int ii = 0; ii < 4; ii++)
#pragma unroll
            for (int jj = 0; jj < 8; jj++) {
                float a = acca[ii][jj] * scale1;
                float v = va[ii][jj];
                v += (a - v) * 0.5f;
                float sc = (v >= 1.0f) ? 1.0f : 0.0f;
                va[ii][jj] = (sc > 0.0f) ? 0.0f : v;
                sat[p_l + ii][nn_l + jj] = sc;
            }
        __syncthreads();

        float acco[2][8];
#pragma unroll
        for (int i = 0; i < 2; i++)
#pragma unroll
            for (int j = 0; j < 8; j++) acco[i][j] = 0.0f;
        for (int p = 0; p < 64; p++) {
            float4 s0 = *(const float4*)&sat[p][nn_l];
            float4 s1 = *(const float4*)&sat[p][nn_l + 4];
            float sv[8] = {s0.x, s0.y, s0.z, s0.w, s1.x, s1.y, s1.z, s1.w};
            float w0 = y2s[d_l][p];
            float w1 = y2s[d_l + 1][p];
#pragma unroll
            for (int jj = 0; jj < 8; jj++) {
                acco[0][jj] = fmaf(w0, sv[jj], acco[0][jj]);
                acco[1][jj] = fmaf(w1, sv[jj], acco[1][jj]);
            }
        }
        unsigned char* og = os + ((size_t)tb * CC + hh * CHD) * HWN + n0;
#pragma unroll
        for (int di = 0; di < 2; di++)
#pragma unroll
            for (int jj = 0; jj < 8; jj++) {
                float a = acco[di][jj] * scale2;
                float v = vo[di][jj];
                v += (a - v) * 0.5f;
                float sc = (v >= 1.0f) ? 1.0f : 0.0f;
                vo[di][jj] = (sc > 0.0f) ? 0.0f : v;
                og[(size_t)(d_l + di) * HWN + nn_l + jj] = (unsigned char)sc;
            }
    }
}

// ---------------- K4: projection GEMM + BN2 + residual -> d_out ----------------
__global__ __launch_bounds__(256) void k_proj(const unsigned char* __restrict__ os,
                                              const float* __restrict__ wp,
                                              const float* __restrict__ g2,
                                              const float* __restrict__ b2,
                                              const float* __restrict__ m2,
                                              const float* __restrict__ vv2,
                                              const float* __restrict__ x,
                                              float* __restrict__ out) {
    __shared__ float wps[32][68];
    __shared__ float ss[32][132];
    int bid = blockIdx.x;
    int tb = bid / 48;
    int rem = bid % 48;
    int o0 = (rem / 8) * 64;
    int n0 = (rem % 8) * 128;
    int tid = threadIdx.x;
    int tx = tid & 15, ty = tid >> 4;
    int hw_l = tx * 8, o_l = ty * 4;
    float acc[4][8];
#pragma unroll
    for (int i = 0; i < 4; i++)
#pragma unroll
        for (int j = 0; j < 8; j++) acc[i][j] = 0.0f;

    for (int kc = 0; kc < CC; kc += 32) {
        __syncthreads();
#pragma unroll
        for (int i = 0; i < 2; i++) {
            int f4 = tid + i * 256;
            int o = f4 >> 3, cb = (f4 & 7) * 4;
            float4 v = *(const float4*)(wp + (size_t)(o0 + o) * CC + kc + cb);
            wps[cb + 0][o] = v.x;
            wps[cb + 1][o] = v.y;
            wps[cb + 2][o] = v.z;
            wps[cb + 3][o] = v.w;
        }
#pragma unroll
        for (int i = 0; i < 4; i++) {
            int u4 = tid + i * 256;
            int kk = u4 >> 5, nb = (u4 & 31) * 4;
            uchar4 v = *(const uchar4*)(os + ((size_t)tb * CC + kc + kk) * HWN + n0 + nb);
            ss[kk][nb + 0] = (float)v.x;
            ss[kk][nb + 1] = (float)v.y;
            ss[kk][nb + 2] = (float)v.z;
            ss[kk][nb + 3] = (float)v.w;
        }
        __syncthreads();
#pragma unroll
        for (int kk = 0; kk < 32; kk++) {
            float4 a4 = *(const float4*)&wps[kk][o_l];
            float4 s0 = *(const float4*)&ss[kk][hw_l];
            float4 s1 = *(const float4*)&ss[kk][hw_l + 4];
            float av[4] = {a4.x, a4.y, a4.z, a4.w};
            float sv[8] = {s0.x, s0.y, s0.z, s0.w, s1.x, s1.y, s1.z, s1.w};
#pragma unroll
            for (int ii = 0; ii < 4; ii++)
#pragma unroll
                for (int jj = 0; jj < 8; jj++)
                    acc[ii][jj] = fmaf(av[ii], sv[jj], acc[ii][jj]);
        }
    }
#pragma unroll
    for (int oi = 0; oi < 4; oi++) {
        int o = o0 + o_l + oi;
        float inv = g2[o] / sqrtf(vv2[o] + 1e-5f);
        float mu = m2[o];
        float bt = b2[o];
        size_t base = ((size_t)tb * CC + o) * HWN + n0 + hw_l;
        float4 xv0 = *(const float4*)(x + base);
        float4 xv1 = *(const float4*)(x + base + 4);
        float4 o0v, o1v;
        o0v.x = (acc[oi][0] - mu) * inv + bt + xv0.x;
        o0v.y = (acc[oi][1] - mu) * inv + bt + xv0.y;
        o0v.z = (acc[oi][2] - mu) * inv + bt + xv0.z;
        o0v.w = (acc[oi][3] - mu) * inv + bt + xv0.w;
        o1v.x = (acc[oi][4] - mu) * inv + bt + xv1.x;
        o1v.y = (acc[oi][5] - mu) * inv + bt + xv1.y;
        o1v.z = (acc[oi][6] - mu) * inv + bt + xv1.z;
        o1v.w = (acc[oi][7] - mu) * inv + bt + xv1.w;
        *(float4*)(out + base) = o0v;
        *(float4*)(out + base + 4) = o1v;
    }
}

extern "C" void kernel_launch(void* const* d_in, const int* in_sizes, int n_in,
                              void* d_out, int out_size, void* d_ws, size_t ws_size,
                              hipStream_t stream) {
    const float* x = (const float*)d_in[0];
    const float* w_conv = (const float*)d_in[1];
    const float* bn1_gamma = (const float*)d_in[2];
    const float* bn1_beta = (const float*)d_in[3];
    const float* bn1_mean = (const float*)d_in[4];
    const float* bn1_var = (const float*)d_in[5];
    const float* w_proj = (const float*)d_in[6];
    const float* bn2_gamma = (const float*)d_in[7];
    const float* bn2_beta = (const float*)d_in[8];
    const float* bn2_mean = (const float*)d_in[9];
    const float* bn2_var = (const float*)d_in[10];
    const float* fr_x = (const float*)d_in[11];
    const float* fr_attn = (const float*)d_in[12];

    // workspace layout
    const size_t SPIKE = (size_t)TT * BB * CC * HWN;     // 12,582,912
    const size_t YB = (size_t)TT * BB * LL * C2 * 4;     // 6,291,456
    const size_t WB = (size_t)KCONV * C2 * 2;            // 9,437,184 (f16)
    const size_t PB = (size_t)MROWS * C2 * 4;            // 6,291,456 per split
    unsigned char* xs = (unsigned char*)d_ws;
    unsigned char* os = xs + SPIKE;
    float* y_t = (float*)(os + SPIKE);
    _Float16* W0 = (_Float16*)((char*)y_t + YB);
    _Float16* W1 = (_Float16*)((char*)W0 + WB);
    char* tail = (char*)W1 + WB;                          // offset 50,331,648

    int KS;
    float* P;
    if (ws_size >= (size_t)(tail - (char*)d_ws) + 8 * PB) {
        KS = 8;
        P = (float*)tail;
    } else if (ws_size >= (size_t)(tail - (char*)d_ws) + 4 * PB) {
        KS = 4;
        P = (float*)tail;
    } else {
        KS = 2;                    // alias P onto os region (os written later by K3)
        P = (float*)os;
    }
    int kbPerSplit = KB_TOT / KS;

    // K0: pack weights (hi/lo f16 split, fragment-major)
    k_pack<<<(KCONV * C2 / 8) / 256, 256, 0, stream>>>(w_conv, W0, W1);
    // K1: LIF on x
    k_lif1<<<(BB * CC * HWN) / 256, 256, 0, stream>>>(x, xs);
    // K2: conv GEMM via MFMA, split-K
    k_conv_mfma<<<dim3(16, 6, KS), 256, 0, stream>>>(xs, W0, W1, P, kbPerSplit);
    // K2b: reduce + BN1
    k_reduce_bn<<<(MROWS * C2) / 256, 256, 0, stream>>>(P, bn1_gamma, bn1_beta, bn1_mean, bn1_var, y_t, KS);
    // K3: fused attention
    k_attn<<<dim3(8, BB * NHEAD), 256, 0, stream>>>(xs, y_t, fr_x, fr_attn, os);
    // K4: projection + BN2 + residual
    k_proj<<<32 * 6 * 8, 256, 0, stream>>>(os, w_proj, bn2_gamma, bn2_beta, bn2_mean, bn2_var, x, (float*)d_out);
}

// Round 3
// 244.624 us; speedup vs baseline: 2.3930x; 1.2739x over previous
//
#include <hip/hip_runtime.h>
#include <math.h>

// Problem dims (fixed)
#define TT 4
#define BB 8
#define CC 384
#define HWN 1024      // 32*32
#define NHEAD 12
#define CHD 32        // C / heads
#define C2 768        // 2*C
#define LL 64         // 8*8 patches
#define KCONV 6144    // C*4*4
#define KB_TOT 192    // KCONV/32
#define MROWS 2048    // TT*BB*64

typedef _Float16 f16x8 __attribute__((ext_vector_type(8)));
typedef _Float16 f16x4 __attribute__((ext_vector_type(4)));
typedef float f32x4 __attribute__((ext_vector_type(4)));

#if defined(__has_builtin)
#if __has_builtin(__builtin_amdgcn_global_load_lds)
#define USE_GLL 1
#endif
#endif
#ifndef USE_GLL
#define USE_GLL 0
#endif

#if USE_GLL
typedef __attribute__((address_space(3))) unsigned int lds_uint;
typedef const __attribute__((address_space(1))) unsigned int glob_uint;
__device__ __forceinline__ void load_lds16(const void* g, void* l) {
    __builtin_amdgcn_global_load_lds((glob_uint*)g, (lds_uint*)l, 16, 0, 0);
}
#endif

// ---------------- K0: pack w_conv into fragment-major f16 hi/lo splits ----------------
// Layout: W[(kb*6+nb)*4096 + q*1024 + col*8 + j], k = kb*32 + q*8 + j, n = nb*128+col.
__global__ __launch_bounds__(256) void k_pack(const float* __restrict__ w,
                                              _Float16* __restrict__ W0,
                                              _Float16* __restrict__ W1) {
    int g = blockIdx.x * 256 + threadIdx.x;   // 0..589823
    int o = g * 8;
    int kbnb = o >> 12;                        // kb*6+nb
    int kb = kbnb / 6;
    int nb = kbnb - kb * 6;
    int q = (o >> 10) & 3;
    int col = (o >> 3) & 127;
    int k = kb * 32 + q * 8;
    int n = nb * 128 + col;
    const float* src = w + (size_t)n * KCONV + k;
    f16x8 h, l;
#pragma unroll
    for (int j = 0; j < 8; j++) {
        float wv = src[j];
        _Float16 hi = (_Float16)wv;
        float rem = (wv - (float)hi) * 2048.0f;
        h[j] = hi;
        l[j] = (_Float16)rem;
    }
    *(f16x8*)(W0 + o) = h;
    *(f16x8*)(W1 + o) = l;
}

// ---------------- K0b: pack w_proj [384][384] into A-fragment-major f16 ----------------
// Layout: Wp[(kb*3+ot)*4096 + q*1024 + row*8 + j], k(c) = kb*32+q*8+j, o = ot*128+row.
__global__ __launch_bounds__(256) void k_pack_wp(const float* __restrict__ wp,
                                                 _Float16* __restrict__ WpH) {
    int g = blockIdx.x * 256 + threadIdx.x;   // 0..18431
    int o8 = g * 8;
    int kbot = o8 >> 12;                       // 0..35
    int kb = kbot / 3;
    int ot = kbot - kb * 3;
    int q = (o8 >> 10) & 3;
    int row = (o8 >> 3) & 127;
    int o = ot * 128 + row;
    int c = kb * 32 + q * 8;
    const float* src = wp + (size_t)o * CC + c;
    f16x8 h;
#pragma unroll
    for (int j = 0; j < 8; j++) h[j] = (_Float16)src[j];
    *(f16x8*)(WpH + o8) = h;
}

// ---------------- K1: LIF over T on x -> spikes u8 ----------------
__global__ __launch_bounds__(256) void k_lif1(const float* __restrict__ x,
                                              unsigned char* __restrict__ xs) {
    const int stride = BB * CC * HWN;
    int idx = blockIdx.x * 256 + threadIdx.x;
    float v = 0.0f;
#pragma unroll
    for (int t = 0; t < TT; t++) {
        float xv = x[(size_t)t * stride + idx];
        v += (xv - v) * 0.5f;
        unsigned char s = (v >= 1.0f) ? 1 : 0;
        xs[(size_t)t * stride + idx] = s;
        if (s) v = 0.0f;
    }
}

// ---------------- K2: conv-as-GEMM via f16 MFMA (hi/lo split), split-K partials ----------------
__global__ __launch_bounds__(256) void k_conv_mfma(const unsigned char* __restrict__ xs,
                                                   const _Float16* __restrict__ W0,
                                                   const _Float16* __restrict__ W1,
                                                   float* __restrict__ P,
                                                   int kbPerSplit) {
    __shared__ __align__(16) _Float16 Asmem[4][128][8];       // 8 KB   [q][row][j]
    __shared__ __align__(16) _Float16 Bsmem[2][4][128][8];    // 16 KB  [split][q][col][j]

    int mt = blockIdx.x;
    int nt = blockIdx.y;
    int s = blockIdx.z;
    int kb0 = s * kbPerSplit;
    int tid = threadIdx.x;
    int wave = tid >> 6;
    int lane = tid & 63;
    int l16 = lane & 15, lq = lane >> 4;
    int wr = (wave & 1) * 64, wc = (wave >> 1) * 64;

    f32x4 acc0[4][4], acc1[4][4];
#pragma unroll
    for (int i = 0; i < 4; i++)
#pragma unroll
        for (int j = 0; j < 4; j++) {
            acc0[i][j] = (f32x4){0.f, 0.f, 0.f, 0.f};
            acc1[i][j] = (f32x4){0.f, 0.f, 0.f, 0.f};
        }

    int row = tid & 127;
    int hf = tid >> 7;                 // 0/1
    int m = mt * 128 + row;
    int tb = m >> 6, pp = m & 63;
    int pi = pp >> 3, pj = pp & 7;
    const unsigned char* xsb = xs + (size_t)tb * (CC * HWN) + (pi * 4) * 32 + pj * 4;

    for (int kb = kb0; kb < kb0 + kbPerSplit; ++kb) {
        __syncthreads();
        const unsigned char* src = xsb + (size_t)(kb * 2 + hf) * HWN;
#pragma unroll
        for (int a = 0; a < 4; ++a) {
            uchar4 u = *(const uchar4*)(src + a * 32);
            f16x4 hv;
            hv[0] = (_Float16)u.x;
            hv[1] = (_Float16)u.y;
            hv[2] = (_Float16)u.z;
            hv[3] = (_Float16)u.w;
            *(f16x4*)&Asmem[2 * hf + (a >> 1)][row][(a & 1) * 4] = hv;
        }
        const char* wb0 = (const char*)W0 + (size_t)(kb * 6 + nt) * 8192;
        const char* wb1 = (const char*)W1 + (size_t)(kb * 6 + nt) * 8192;
#if USE_GLL
#pragma unroll
        for (int i = 0; i < 4; ++i) {
            int off = (wave * 4 + i) * 1024;
            const char* wb = (off & 8192) ? wb1 : wb0;
            load_lds16(wb + (off & 8191) + lane * 16, (char*)&Bsmem[0][0][0][0] + off);
        }
#else
#pragma unroll
        for (int i = 0; i < 4; ++i) {
            int off = (tid + i * 256) * 16;
            const char* wb = (off & 8192) ? wb1 : wb0;
            *(float4*)((char*)&Bsmem[0][0][0][0] + off) = *(const float4*)(wb + (off & 8191));
        }
#endif
        __syncthreads();

        f16x8 af[4], bf0[4], bf1[4];
#pragma unroll
        for (int fi = 0; fi < 4; fi++) af[fi] = *(const f16x8*)&Asmem[lq][wr + fi * 16 + l16][0];
#pragma unroll
        for (int fj = 0; fj < 4; fj++) {
            bf0[fj] = *(const f16x8*)&Bsmem[0][lq][wc + fj * 16 + l16][0];
            bf1[fj] = *(const f16x8*)&Bsmem[1][lq][wc + fj * 16 + l16][0];
        }
#pragma unroll
        for (int fi = 0; fi < 4; fi++)
#pragma unroll
            for (int fj = 0; fj < 4; fj++) {
                acc0[fi][fj] = __builtin_amdgcn_mfma_f32_16x16x32_f16(af[fi], bf0[fj], acc0[fi][fj], 0, 0, 0);
                acc1[fi][fj] = __builtin_amdgcn_mfma_f32_16x16x32_f16(af[fi], bf1[fj], acc1[fi][fj], 0, 0, 0);
            }
    }

    size_t Pbase = (size_t)s * MROWS * C2;
#pragma unroll
    for (int fi = 0; fi < 4; fi++)
#pragma unroll
        for (int fj = 0; fj < 4; fj++) {
            int ccol = nt * 128 + wc + fj * 16 + l16;
#pragma unroll
            for (int r = 0; r < 4; r++) {
                int rr = mt * 128 + wr + fi * 16 + lq * 4 + r;
                float v = acc0[fi][fj][r] + acc1[fi][fj][r] * (1.0f / 2048.0f);
                P[Pbase + (size_t)rr * C2 + ccol] = v;
            }
        }
}

// ---------------- K2b: reduce split-K partials + BN1 -> y_t [tb][pp][oc] ----------------
__global__ __launch_bounds__(256) void k_reduce_bn(const float* __restrict__ P,
                                                   const float* __restrict__ g1,
                                                   const float* __restrict__ b1,
                                                   const float* __restrict__ m1,
                                                   const float* __restrict__ v1,
                                                   float* __restrict__ y_t,
                                                   int KS) {
    int e = blockIdx.x * 256 + threadIdx.x;
    float sum = 0.0f;
    for (int s = 0; s < KS; s++) sum += P[(size_t)s * MROWS * C2 + e];
    int n = e % C2;
    float inv = g1[n] / sqrtf(v1[n] + 1e-5f);
    y_t[e] = (sum - m1[n]) * inv + b1[n];
}

// ---------------- K3: fused attention -> OsF (f16 B-fragment layout for proj) ----------------
// OsF region per (tb, hh, ntile): 4096 halfs, element (d,n): q*1024 + n*8 + j, q=d>>3, j=d&7.
__global__ __launch_bounds__(256) void k_attn(const unsigned char* __restrict__ xs,
                                              const float* __restrict__ y_t,
                                              const float* __restrict__ fr_x,
                                              const float* __restrict__ fr_attn,
                                              _Float16* __restrict__ OsF) {
    __shared__ float y1s[32][68];
    __shared__ float y2s[32][68];
    __shared__ float xrs[32][132];
    __shared__ float sat[64][132];

    int n0 = blockIdx.x * 128;
    int bh = blockIdx.y;
    int b = bh / NHEAD, hh = bh % NHEAD;
    int tid = threadIdx.x;
    int tx = tid & 15, ty = tid >> 4;
    int nn_l = tx * 8;
    int p_l = ty * 4;
    int d_l = ty * 2;

    float scale1 = 1.0f / sqrtf(fr_x[hh] * 32.0f);
    float scale2 = 1.0f / sqrtf(fr_attn[hh] * 64.0f);

    float va[4][8];
    float vo[2][8];
#pragma unroll
    for (int i = 0; i < 4; i++)
#pragma unroll
        for (int j = 0; j < 8; j++) va[i][j] = 0.0f;
#pragma unroll
    for (int i = 0; i < 2; i++)
#pragma unroll
        for (int j = 0; j < 8; j++) vo[i][j] = 0.0f;

    for (int t = 0; t < TT; t++) {
        __syncthreads();
        int tb = t * BB + b;
        const float* yg = y_t + (size_t)tb * (LL * C2) + hh * 64;
#pragma unroll
        for (int i = 0; i < 16; i++) {
            int f = i * 256 + tid;
            int p = f >> 6, dc = f & 63;
            float v = yg[(size_t)p * C2 + dc];
            if (dc < 32) y1s[dc][p] = v;
            else y2s[dc - 32][p] = v;
        }
        const unsigned char* xg = xs + ((size_t)tb * CC + hh * CHD) * HWN + n0;
#pragma unroll
        for (int i = 0; i < 4; i++) {
            int u4 = tid + i * 256;
            int d = u4 >> 5, nb = (u4 & 31) * 4;
            uchar4 v = *(const uchar4*)(xg + (size_t)d * HWN + nb);
            xrs[d][nb + 0] = (float)v.x;
            xrs[d][nb + 1] = (float)v.y;
            xrs[d][nb + 2] = (float)v.z;
            xrs[d][nb + 3] = (float)v.w;
        }
        __syncthreads();

        float acca[4][8];
#pragma unroll
        for (int i = 0; i < 4; i++)
#pragma unroll
            for (int j = 0; j < 8; j++) acca[i][j] = 0.0f;
        for (int d = 0; d < 32; d++) {
            float4 a4 = *(const float4*)&y1s[d][p_l];
            float4 x0 = *(const float4*)&xrs[d][nn_l];
            float4 x1 = *(const float4*)&xrs[d][nn_l + 4];
            float av[4] = {a4.x, a4.y, a4.z, a4.w};
            float xv[8] = {x0.x, x0.y, x0.z, x0.w, x1.x, x1.y, x1.z, x1.w};
#pragma unroll
            for (int ii = 0; ii < 4; ii++)
#pragma unroll
                for (int jj = 0; jj < 8; jj++)
                    acca[ii][jj] = fmaf(av[ii], xv[jj], acca[ii][jj]);
        }
#pragma unroll
        for (int ii = 0; ii < 4; ii++)
#pragma unroll
            for (int jj = 0; jj < 8; jj++) {
                float a = acca[ii][jj] * scale1;
                float v = va[ii][jj];
                v += (a - v) * 0.5f;
                float sc = (v >= 1.0f) ? 1.0f : 0.0f;
                va[ii][jj] = (sc > 0.0f) ? 0.0f : v;
                sat[p_l + ii][nn_l + jj] = sc;
            }
        __syncthreads();

        float acco[2][8];
#pragma unroll
        for (int i = 0; i < 2; i++)
#pragma unroll
            for (int j = 0; j < 8; j++) acco[i][j] = 0.0f;
        for (int p = 0; p < 64; p++) {
            float4 s0 = *(const float4*)&sat[p][nn_l];
            float4 s1 = *(const float4*)&sat[p][nn_l + 4];
            float sv[8] = {s0.x, s0.y, s0.z, s0.w, s1.x, s1.y, s1.z, s1.w};
            float w0 = y2s[d_l][p];
            float w1 = y2s[d_l + 1][p];
#pragma unroll
            for (int jj = 0; jj < 8; jj++) {
                acco[0][jj] = fmaf(w0, sv[jj], acco[0][jj]);
                acco[1][jj] = fmaf(w1, sv[jj], acco[1][jj]);
            }
        }
        _Float16* ogf = OsF + ((size_t)(tb * NHEAD + hh) * 8 + blockIdx.x) * 4096;
#pragma unroll
        for (int di = 0; di < 2; di++)
#pragma unroll
            for (int jj = 0; jj < 8; jj++) {
                float a = acco[di][jj] * scale2;
                float v = vo[di][jj];
                v += (a - v) * 0.5f;
                float sc = (v >= 1.0f) ? 1.0f : 0.0f;
                vo[di][jj] = (sc > 0.0f) ? 0.0f : v;
                int d = d_l + di, n = nn_l + jj;
                ogf[(d >> 3) * 1024 + n * 8 + (d & 7)] = (_Float16)sc;
            }
    }
}

// ---------------- K4: projection GEMM via MFMA + BN2 + residual -> d_out ----------------
// grid (8 ntiles, 3 otiles, 32 tb). 4 waves, each 64x64.
__global__ __launch_bounds__(256) void k_proj_mfma(const _Float16* __restrict__ OsF,
                                                   const _Float16* __restrict__ WpH,
                                                   const float* __restrict__ g2,
                                                   const float* __restrict__ b2,
                                                   const float* __restrict__ m2,
                                                   const float* __restrict__ vv2,
                                                   const float* __restrict__ x,
                                                   float* __restrict__ out) {
    __shared__ __align__(16) _Float16 Bs[4][128][8];    // 8 KB spikes [q][n][j]

    int nt = blockIdx.x;
    int ot = blockIdx.y;
    int tb = blockIdx.z;
    int tid = threadIdx.x;
    int wave = tid >> 6;
    int lane = tid & 63;
    int l16 = lane & 15, lq = lane >> 4;
    int wr = (wave & 1) * 64, wc = (wave >> 1) * 64;

    f32x4 acc[4][4];
#pragma unroll
    for (int i = 0; i < 4; i++)
#pragma unroll
        for (int j = 0; j < 4; j++) acc[i][j] = (f32x4){0.f, 0.f, 0.f, 0.f};

    for (int kb = 0; kb < 12; ++kb) {
        __syncthreads();
        // stage spikes: 8 KB linear copy (fragment layout already)
        const char* src = (const char*)(OsF + ((size_t)(tb * NHEAD + kb) * 8 + nt) * 4096);
#if USE_GLL
#pragma unroll
        for (int i = 0; i < 2; ++i) {
            int off = (tid + i * 256) * 16;
            load_lds16(src + off, (char*)&Bs[0][0][0] + off);
        }
#else
#pragma unroll
        for (int i = 0; i < 2; ++i) {
            int off = (tid + i * 256) * 16;
            *(float4*)((char*)&Bs[0][0][0] + off) = *(const float4*)(src + off);
        }
#endif
        // A frags direct from global (L2-resident packed weights)
        const _Float16* wbase = WpH + (size_t)(kb * 3 + ot) * 4096 + lq * 1024;
        f16x8 af[4];
#pragma unroll
        for (int fi = 0; fi < 4; fi++)
            af[fi] = *(const f16x8*)(wbase + (size_t)(wr + fi * 16 + l16) * 8);
        __syncthreads();

        f16x8 bf[4];
#pragma unroll
        for (int fj = 0; fj < 4; fj++)
            bf[fj] = *(const f16x8*)&Bs[lq][wc + fj * 16 + l16][0];
#pragma unroll
        for (int fi = 0; fi < 4; fi++)
#pragma unroll
            for (int fj = 0; fj < 4; fj++)
                acc[fi][fj] = __builtin_amdgcn_mfma_f32_16x16x32_f16(af[fi], bf[fj], acc[fi][fj], 0, 0, 0);
    }

    // epilogue: BN2 + residual
    size_t orow_base = (size_t)tb * CC * HWN;
    int n_base = nt * 128 + wc;
#pragma unroll
    for (int fi = 0; fi < 4; fi++) {
        float invv[4], muv[4], btv[4];
#pragma unroll
        for (int r = 0; r < 4; r++) {
            int o = ot * 128 + wr + fi * 16 + lq * 4 + r;
            invv[r] = g2[o] / sqrtf(vv2[o] + 1e-5f);
            muv[r] = m2[o];
            btv[r] = b2[o];
        }
#pragma unroll
        for (int fj = 0; fj < 4; fj++) {
#pragma unroll
            for (int r = 0; r < 4; r++) {
                int o = ot * 128 + wr + fi * 16 + lq * 4 + r;
                size_t addr = orow_base + (size_t)o * HWN + n_base + fj * 16 + l16;
                out[addr] = (acc[fi][fj][r] - muv[r]) * invv[r] + btv[r] + x[addr];
            }
        }
    }
}

extern "C" void kernel_launch(void* const* d_in, const int* in_sizes, int n_in,
                              void* d_out, int out_size, void* d_ws, size_t ws_size,
                              hipStream_t stream) {
    const float* x = (const float*)d_in[0];
    const float* w_conv = (const float*)d_in[1];
    const float* bn1_gamma = (const float*)d_in[2];
    const float* bn1_beta = (const float*)d_in[3];
    const float* bn1_mean = (const float*)d_in[4];
    const float* bn1_var = (const float*)d_in[5];
    const float* w_proj = (const float*)d_in[6];
    const float* bn2_gamma = (const float*)d_in[7];
    const float* bn2_beta = (const float*)d_in[8];
    const float* bn2_mean = (const float*)d_in[9];
    const float* bn2_var = (const float*)d_in[10];
    const float* fr_x = (const float*)d_in[11];
    const float* fr_attn = (const float*)d_in[12];

    // workspace layout
    const size_t SPIKE = (size_t)TT * BB * CC * HWN;        // 12,582,912 (u8 xs)
    const size_t OSF_B = (size_t)TT * BB * NHEAD * 8 * 4096 * 2;  // 25,165,824 (f16 frag spikes)
    const size_t YB = (size_t)TT * BB * LL * C2 * 4;        // 6,291,456
    const size_t WB = (size_t)KCONV * C2 * 2;               // 9,437,184 (f16)
    const size_t WPB = (size_t)CC * CC * 2;                 // 294,912 (f16)
    const size_t PB = (size_t)MROWS * C2 * 4;               // 6,291,456 per split
    unsigned char* xs = (unsigned char*)d_ws;
    _Float16* OsF = (_Float16*)(xs + SPIKE);
    float* y_t = (float*)((char*)OsF + OSF_B);
    _Float16* W0 = (_Float16*)((char*)y_t + YB);
    _Float16* W1 = (_Float16*)((char*)W0 + WB);
    _Float16* WpH = (_Float16*)((char*)W1 + WB);
    char* tail = (char*)WpH + WPB;

    int KS;
    float* P;
    if (ws_size >= (size_t)(tail - (char*)d_ws) + 8 * PB) {
        KS = 8;
        P = (float*)tail;
    } else if (ws_size >= (size_t)(tail - (char*)d_ws) + 4 * PB) {
        KS = 4;
        P = (float*)tail;
    } else {
        KS = 2;                    // alias P onto OsF region (OsF written later by K3)
        P = (float*)OsF;
    }
    int kbPerSplit = KB_TOT / KS;

    // K0: pack conv weights (hi/lo f16 split, fragment-major)
    k_pack<<<(KCONV * C2 / 8) / 256, 256, 0, stream>>>(w_conv, W0, W1);
    // K0b: pack proj weights (f16, A-fragment-major)
    k_pack_wp<<<(CC * CC / 8) / 256, 256, 0, stream>>>(w_proj, WpH);
    // K1: LIF on x
    k_lif1<<<(BB * CC * HWN) / 256, 256, 0, stream>>>(x, xs);
    // K2: conv GEMM via MFMA, split-K
    k_conv_mfma<<<dim3(16, 6, KS), 256, 0, stream>>>(xs, W0, W1, P, kbPerSplit);
    // K2b: reduce + BN1
    k_reduce_bn<<<(MROWS * C2) / 256, 256, 0, stream>>>(P, bn1_gamma, bn1_beta, bn1_mean, bn1_var, y_t, KS);
    // K3: fused attention -> f16 fragment spikes
    k_attn<<<dim3(8, BB * NHEAD), 256, 0, stream>>>(xs, y_t, fr_x, fr_attn, OsF);
    // K4: projection MFMA + BN2 + residual
    k_proj_mfma<<<dim3(8, 3, 32), 256, 0, stream>>>(OsF, WpH, bn2_gamma, bn2_beta, bn2_mean, bn2_var, x, (float*)d_out);
}

// Round 4
// 173.578 us; speedup vs baseline: 3.3725x; 1.4093x over previous
//
#include <hip/hip_runtime.h>
#include <math.h>

// Problem dims (fixed)
#define TT 4
#define BB 8
#define CC 384
#define HWN 1024      // 32*32
#define NHEAD 12
#define CHD 32        // C / heads
#define C2 768        // 2*C
#define LL 64         // 8*8 patches
#define KCONV 6144    // C*4*4
#define KB_TOT 192    // KCONV/32
#define MROWS 2048    // TT*BB*64

typedef _Float16 f16x8 __attribute__((ext_vector_type(8)));
typedef _Float16 f16x4 __attribute__((ext_vector_type(4)));
typedef float f32x4 __attribute__((ext_vector_type(4)));

#if defined(__has_builtin)
#if __has_builtin(__builtin_amdgcn_global_load_lds)
#define USE_GLL 1
#endif
#endif
#ifndef USE_GLL
#define USE_GLL 0
#endif

#if USE_GLL
typedef __attribute__((address_space(3))) unsigned int lds_uint;
typedef const __attribute__((address_space(1))) unsigned int glob_uint;
__device__ __forceinline__ void load_lds16(const void* g, void* l) {
    __builtin_amdgcn_global_load_lds((glob_uint*)g, (lds_uint*)l, 16, 0, 0);
}
#endif

// ---------------- K0: pack w_conv into fragment-major f16 hi/lo splits ----------------
__global__ __launch_bounds__(256) void k_pack(const float* __restrict__ w,
                                              _Float16* __restrict__ W0,
                                              _Float16* __restrict__ W1) {
    int g = blockIdx.x * 256 + threadIdx.x;   // 0..589823
    int o = g * 8;
    int kbnb = o >> 12;                        // kb*6+nb
    int kb = kbnb / 6;
    int nb = kbnb - kb * 6;
    int q = (o >> 10) & 3;
    int col = (o >> 3) & 127;
    int k = kb * 32 + q * 8;
    int n = nb * 128 + col;
    const float* src = w + (size_t)n * KCONV + k;
    f16x8 h, l;
#pragma unroll
    for (int j = 0; j < 8; j++) {
        float wv = src[j];
        _Float16 hi = (_Float16)wv;
        float rem = (wv - (float)hi) * 2048.0f;
        h[j] = hi;
        l[j] = (_Float16)rem;
    }
    *(f16x8*)(W0 + o) = h;
    *(f16x8*)(W1 + o) = l;
}

// ---------------- K0b: pack w_proj [384][384] into A-fragment-major f16 ----------------
__global__ __launch_bounds__(256) void k_pack_wp(const float* __restrict__ wp,
                                                 _Float16* __restrict__ WpH) {
    int g = blockIdx.x * 256 + threadIdx.x;   // 0..18431
    int o8 = g * 8;
    int kbot = o8 >> 12;                       // 0..35
    int kb = kbot / 3;
    int ot = kbot - kb * 3;
    int q = (o8 >> 10) & 3;
    int row = (o8 >> 3) & 127;
    int o = ot * 128 + row;
    int c = kb * 32 + q * 8;
    const float* src = wp + (size_t)o * CC + c;
    f16x8 h;
#pragma unroll
    for (int j = 0; j < 8; j++) h[j] = (_Float16)src[j];
    *(f16x8*)(WpH + o8) = h;
}

// ---------------- K1: LIF over T on x -> xs (u8 planar) + xsF (f16 B-frag per (tb,hh,nt)) ----------------
// xsF region (tb,hh,nt): [q=4][n=128][j=8], d = hh-local channel = q*8+j.
// grid dim3(16, 96): x = q*4 + nt256, y = b*12 + hh.
__global__ __launch_bounds__(256) void k_lif1(const float* __restrict__ x,
                                              unsigned char* __restrict__ xs,
                                              _Float16* __restrict__ xsF) {
    int nt = blockIdx.x & 3, q = blockIdx.x >> 2;
    int bh = blockIdx.y;
    int b = bh / NHEAD, hh = bh % NHEAD;
    int n = nt * 256 + threadIdx.x;
    const int stride = BB * CC * HWN;
    size_t base0 = ((size_t)b * CC + hh * 32 + q * 8) * HWN + n;
    f16x8 frag[4];
#pragma unroll
    for (int j = 0; j < 8; j++) {
        float v = 0.0f;
        size_t off = base0 + (size_t)j * HWN;
#pragma unroll
        for (int t = 0; t < TT; t++) {
            float xv = x[(size_t)t * stride + off];
            v += (xv - v) * 0.5f;
            float s = (v >= 1.0f) ? 1.0f : 0.0f;
            if (s > 0.0f) v = 0.0f;
            xs[(size_t)t * stride + off] = (unsigned char)s;
            frag[t][j] = (_Float16)s;
        }
    }
#pragma unroll
    for (int t = 0; t < TT; t++) {
        int tb = t * BB + b;
        size_t dst = ((size_t)(tb * NHEAD + hh) * 8 + (n >> 7)) * 4096 + q * 1024 + (size_t)(n & 127) * 8;
        *(f16x8*)(xsF + dst) = frag[t];
    }
}

// ---------------- K2: conv-as-GEMM via f16 MFMA (hi/lo split), split-K partials ----------------
__global__ __launch_bounds__(256) void k_conv_mfma(const unsigned char* __restrict__ xs,
                                                   const _Float16* __restrict__ W0,
                                                   const _Float16* __restrict__ W1,
                                                   float* __restrict__ P,
                                                   int kbPerSplit) {
    __shared__ __align__(16) _Float16 Asmem[4][128][8];       // 8 KB
    __shared__ __align__(16) _Float16 Bsmem[2][4][128][8];    // 16 KB

    int mt = blockIdx.x;
    int nt = blockIdx.y;
    int s = blockIdx.z;
    int kb0 = s * kbPerSplit;
    int tid = threadIdx.x;
    int wave = tid >> 6;
    int lane = tid & 63;
    int l16 = lane & 15, lq = lane >> 4;
    int wr = (wave & 1) * 64, wc = (wave >> 1) * 64;

    f32x4 acc0[4][4], acc1[4][4];
#pragma unroll
    for (int i = 0; i < 4; i++)
#pragma unroll
        for (int j = 0; j < 4; j++) {
            acc0[i][j] = (f32x4){0.f, 0.f, 0.f, 0.f};
            acc1[i][j] = (f32x4){0.f, 0.f, 0.f, 0.f};
        }

    int row = tid & 127;
    int hf = tid >> 7;
    int m = mt * 128 + row;
    int tb = m >> 6, pp = m & 63;
    int pi = pp >> 3, pj = pp & 7;
    const unsigned char* xsb = xs + (size_t)tb * (CC * HWN) + (pi * 4) * 32 + pj * 4;

    for (int kb = kb0; kb < kb0 + kbPerSplit; ++kb) {
        __syncthreads();
        const unsigned char* src = xsb + (size_t)(kb * 2 + hf) * HWN;
#pragma unroll
        for (int a = 0; a < 4; ++a) {
            uchar4 u = *(const uchar4*)(src + a * 32);
            f16x4 hv;
            hv[0] = (_Float16)u.x;
            hv[1] = (_Float16)u.y;
            hv[2] = (_Float16)u.z;
            hv[3] = (_Float16)u.w;
            *(f16x4*)&Asmem[2 * hf + (a >> 1)][row][(a & 1) * 4] = hv;
        }
        const char* wb0 = (const char*)W0 + (size_t)(kb * 6 + nt) * 8192;
        const char* wb1 = (const char*)W1 + (size_t)(kb * 6 + nt) * 8192;
#if USE_GLL
#pragma unroll
        for (int i = 0; i < 4; ++i) {
            int off = (wave * 4 + i) * 1024;
            const char* wb = (off & 8192) ? wb1 : wb0;
            load_lds16(wb + (off & 8191) + lane * 16, (char*)&Bsmem[0][0][0][0] + off);
        }
#else
#pragma unroll
        for (int i = 0; i < 4; ++i) {
            int off = (tid + i * 256) * 16;
            const char* wb = (off & 8192) ? wb1 : wb0;
            *(float4*)((char*)&Bsmem[0][0][0][0] + off) = *(const float4*)(wb + (off & 8191));
        }
#endif
        __syncthreads();

        f16x8 af[4], bf0[4], bf1[4];
#pragma unroll
        for (int fi = 0; fi < 4; fi++) af[fi] = *(const f16x8*)&Asmem[lq][wr + fi * 16 + l16][0];
#pragma unroll
        for (int fj = 0; fj < 4; fj++) {
            bf0[fj] = *(const f16x8*)&Bsmem[0][lq][wc + fj * 16 + l16][0];
            bf1[fj] = *(const f16x8*)&Bsmem[1][lq][wc + fj * 16 + l16][0];
        }
#pragma unroll
        for (int fi = 0; fi < 4; fi++)
#pragma unroll
            for (int fj = 0; fj < 4; fj++) {
                acc0[fi][fj] = __builtin_amdgcn_mfma_f32_16x16x32_f16(af[fi], bf0[fj], acc0[fi][fj], 0, 0, 0);
                acc1[fi][fj] = __builtin_amdgcn_mfma_f32_16x16x32_f16(af[fi], bf1[fj], acc1[fi][fj], 0, 0, 0);
            }
    }

    size_t Pbase = (size_t)s * MROWS * C2;
#pragma unroll
    for (int fi = 0; fi < 4; fi++)
#pragma unroll
        for (int fj = 0; fj < 4; fj++) {
            int ccol = nt * 128 + wc + fj * 16 + l16;
#pragma unroll
            for (int r = 0; r < 4; r++) {
                int rr = mt * 128 + wr + fi * 16 + lq * 4 + r;
                float v = acc0[fi][fj][r] + acc1[fi][fj][r] * (1.0f / 2048.0f);
                P[Pbase + (size_t)rr * C2 + ccol] = v;
            }
        }
}

// ---------------- K2b: reduce split-K + BN1 -> A1/A2 hi-lo f16 fragments per (tb,hh) ----------------
// A1 region (tb,hh): [hl=2][2048]: addr = ((pp>>4)*4 + (d>>3))*128 + (pp&15)*8 + (d&7)   (y1[d][pp])
// A2 region (tb,hh): [hl=2][2048]: addr = ((dt*8+ks*4+lq)*16 + d16)*8 + j  (y2[dt*16+d16][ks*32+lq*8+j])
__global__ __launch_bounds__(256) void k_reduce_frag(const float* __restrict__ P,
                                                     const float* __restrict__ g1,
                                                     const float* __restrict__ b1,
                                                     const float* __restrict__ m1,
                                                     const float* __restrict__ v1,
                                                     _Float16* __restrict__ A1,
                                                     _Float16* __restrict__ A2,
                                                     int KS) {
    __shared__ float y2ls[32][66];
    int tb = blockIdx.x / NHEAD, hh = blockIdx.x % NHEAD;
    int tid = threadIdx.x;
    int pp = tid >> 2, cq = (tid & 3) * 16;

    size_t rowbase = ((size_t)tb * 64 + pp) * C2 + hh * 64 + cq;
    float yv[16];
#pragma unroll
    for (int i = 0; i < 16; i++) yv[i] = 0.0f;
    for (int s = 0; s < KS; s++) {
        const float* p = P + (size_t)s * MROWS * C2 + rowbase;
#pragma unroll
        for (int i4 = 0; i4 < 4; i4++) {
            float4 v = *(const float4*)(p + i4 * 4);
            yv[i4 * 4 + 0] += v.x;
            yv[i4 * 4 + 1] += v.y;
            yv[i4 * 4 + 2] += v.z;
            yv[i4 * 4 + 3] += v.w;
        }
    }
#pragma unroll
    for (int i = 0; i < 16; i++) {
        int oc = hh * 64 + cq + i;
        float inv = g1[oc] / sqrtf(v1[oc] + 1e-5f);
        yv[i] = (yv[i] - m1[oc]) * inv + b1[oc];
    }

    size_t reg = (size_t)(tb * NHEAD + hh) * 4096;
    if (cq < 32) {
        // y1 -> A1 direct (j = d&7 contiguous)
#pragma unroll
        for (int gi = 0; gi < 2; gi++) {
            int c0 = cq + gi * 8;
            f16x8 h, l;
#pragma unroll
            for (int j = 0; j < 8; j++) {
                float v = yv[gi * 8 + j];
                _Float16 hi = (_Float16)v;
                h[j] = hi;
                l[j] = (_Float16)((v - (float)hi) * 2048.0f);
            }
            size_t a = reg + (size_t)(((pp >> 4) * 4 + (c0 >> 3)) * 128 + (pp & 15) * 8);
            *(f16x8*)(A1 + a) = h;
            *(f16x8*)(A1 + a + 2048) = l;
        }
    } else {
        // y2 -> LDS staging [d][pp]
#pragma unroll
        for (int i = 0; i < 16; i++) y2ls[cq - 32 + i][pp] = yv[i];
    }
    __syncthreads();
    // A2 emit: 256 threads x 2 passes (hi/lo), each one f16x8
    int d16 = tid & 15, grp = tid >> 4;        // grp = dt*8 + ks*4 + lq
    int dt = grp >> 3, ks = (grp >> 2) & 1, lq = grp & 3;
    int d = dt * 16 + d16, p0 = ks * 32 + lq * 8;
    f16x8 h, l;
#pragma unroll
    for (int j = 0; j < 8; j++) {
        float v = y2ls[d][p0 + j];
        _Float16 hi = (_Float16)v;
        h[j] = hi;
        l[j] = (_Float16)((v - (float)hi) * 2048.0f);
    }
    size_t a = reg + (size_t)((grp * 16 + d16) * 8);
    *(f16x8*)(A2 + a) = h;
    *(f16x8*)(A2 + a + 2048) = l;
}

// ---------------- K3: fused attention via MFMA -> OsF ----------------
// grid dim3(8, 96): x = nt (n-tile 128), y = b*12+hh. 4 waves.
__global__ __launch_bounds__(256) void k_attn_mfma(const _Float16* __restrict__ xsF,
                                                   const _Float16* __restrict__ A1,
                                                   const _Float16* __restrict__ A2,
                                                   const float* __restrict__ fr_x,
                                                   const float* __restrict__ fr_attn,
                                                   _Float16* __restrict__ OsF) {
    __shared__ __align__(16) _Float16 Bs[4][128][8];    // 8 KB xr tile
    __shared__ __align__(16) _Float16 Sat[8][128][8];   // 16 KB attn spikes

    int nt = blockIdx.x;
    int bh = blockIdx.y;
    int b = bh / NHEAD, hh = bh % NHEAD;
    int tid = threadIdx.x;
    int w = tid >> 6;
    int lane = tid & 63;
    int l16 = lane & 15, lq = lane >> 4;

    float scale1 = 1.0f / sqrtf(fr_x[hh] * 32.0f);
    float scale2 = 1.0f / sqrtf(fr_attn[hh] * 64.0f);

    float va[8][4];                 // attn LIF state: p = w*16+lq*4+r, n = nf*16+l16
    float vo[2][2][4];              // out LIF state: d = dt*16+lq*4+r, n = w*32+nf2*16+l16
#pragma unroll
    for (int nf = 0; nf < 8; nf++)
#pragma unroll
        for (int r = 0; r < 4; r++) va[nf][r] = 0.0f;
#pragma unroll
    for (int dt = 0; dt < 2; dt++)
#pragma unroll
        for (int nf = 0; nf < 2; nf++)
#pragma unroll
            for (int r = 0; r < 4; r++) vo[dt][nf][r] = 0.0f;

    for (int t = 0; t < TT; t++) {
        int tb = t * BB + b;
        size_t reg = (size_t)(tb * NHEAD + hh);
        // stage xr tile (linear 8 KB)
        const char* src = (const char*)(xsF + (reg * 8 + nt) * 4096);
#if USE_GLL
        load_lds16(src + tid * 16, (char*)&Bs[0][0][0] + tid * 16);
        load_lds16(src + tid * 16 + 4096, (char*)&Bs[0][0][0] + tid * 16 + 4096);
#else
        *(float4*)((char*)&Bs[0][0][0] + tid * 16) = *(const float4*)(src + tid * 16);
        *(float4*)((char*)&Bs[0][0][0] + tid * 16 + 4096) = *(const float4*)(src + tid * 16 + 4096);
#endif
        // A1 frags (direct from global)
        const _Float16* a1b = A1 + reg * 4096;
        f16x8 a1h = *(const f16x8*)(a1b + (size_t)(((w * 4 + lq) * 16 + l16) * 8));
        f16x8 a1l = *(const f16x8*)(a1b + 2048 + (size_t)(((w * 4 + lq) * 16 + l16) * 8));
        __syncthreads();

        // einsum1: wave w -> p-tile w, all 8 n-frags
        f32x4 ah[8], al[8];
#pragma unroll
        for (int nf = 0; nf < 8; nf++) {
            ah[nf] = (f32x4){0.f, 0.f, 0.f, 0.f};
            al[nf] = (f32x4){0.f, 0.f, 0.f, 0.f};
        }
#pragma unroll
        for (int nf = 0; nf < 8; nf++) {
            f16x8 bf = *(const f16x8*)&Bs[lq][nf * 16 + l16][0];
            ah[nf] = __builtin_amdgcn_mfma_f32_16x16x32_f16(a1h, bf, ah[nf], 0, 0, 0);
            al[nf] = __builtin_amdgcn_mfma_f32_16x16x32_f16(a1l, bf, al[nf], 0, 0, 0);
        }
        // attn LIF -> spikes into Sat (B-frag layout, k=p)
        int pq = w * 2 + (lq >> 1);
#pragma unroll
        for (int nf = 0; nf < 8; nf++) {
            f16x4 sp;
#pragma unroll
            for (int r = 0; r < 4; r++) {
                float a = (ah[nf][r] + al[nf][r] * (1.0f / 2048.0f)) * scale1;
                float v = va[nf][r];
                v += (a - v) * 0.5f;
                float s = (v >= 1.0f) ? 1.0f : 0.0f;
                va[nf][r] = (s > 0.0f) ? 0.0f : v;
                sp[r] = (_Float16)s;
            }
            *(f16x4*)&Sat[pq][nf * 16 + l16][(lq & 1) * 4] = sp;
        }
        __syncthreads();

        // einsum2: wave w -> n cols w*32..w*32+31 (2 n-frags), d 0..31
        const _Float16* a2b = A2 + reg * 4096;
        f32x4 oh[2][2], ol[2][2];
#pragma unroll
        for (int dt = 0; dt < 2; dt++)
#pragma unroll
            for (int nf = 0; nf < 2; nf++) {
                oh[dt][nf] = (f32x4){0.f, 0.f, 0.f, 0.f};
                ol[dt][nf] = (f32x4){0.f, 0.f, 0.f, 0.f};
            }
#pragma unroll
        for (int ks = 0; ks < 2; ks++) {
            f16x8 bf0 = *(const f16x8*)&Sat[ks * 4 + lq][w * 32 + l16][0];
            f16x8 bf1 = *(const f16x8*)&Sat[ks * 4 + lq][w * 32 + 16 + l16][0];
#pragma unroll
            for (int dt = 0; dt < 2; dt++) {
                size_t ao = (size_t)(((dt * 8 + ks * 4 + lq) * 16 + l16) * 8);
                f16x8 a2h = *(const f16x8*)(a2b + ao);
                f16x8 a2l = *(const f16x8*)(a2b + 2048 + ao);
                oh[dt][0] = __builtin_amdgcn_mfma_f32_16x16x32_f16(a2h, bf0, oh[dt][0], 0, 0, 0);
                ol[dt][0] = __builtin_amdgcn_mfma_f32_16x16x32_f16(a2l, bf0, ol[dt][0], 0, 0, 0);
                oh[dt][1] = __builtin_amdgcn_mfma_f32_16x16x32_f16(a2h, bf1, oh[dt][1], 0, 0, 0);
                ol[dt][1] = __builtin_amdgcn_mfma_f32_16x16x32_f16(a2l, bf1, ol[dt][1], 0, 0, 0);
            }
        }
        // out LIF -> OsF spikes (B-frag layout for proj)
        _Float16* og = OsF + (reg * 8 + nt) * 4096;
#pragma unroll
        for (int dt = 0; dt < 2; dt++)
#pragma unroll
            for (int nf = 0; nf < 2; nf++) {
                f16x4 sp;
#pragma unroll
                for (int r = 0; r < 4; r++) {
                    float a = (oh[dt][nf][r] + ol[dt][nf][r] * (1.0f / 2048.0f)) * scale2;
                    float v = vo[dt][nf][r];
                    v += (a - v) * 0.5f;
                    float s = (v >= 1.0f) ? 1.0f : 0.0f;
                    vo[dt][nf][r] = (s > 0.0f) ? 0.0f : v;
                    sp[r] = (_Float16)s;
                }
                int n = w * 32 + nf * 16 + l16;
                *(f16x4*)(og + (size_t)((dt * 2 + (lq >> 1)) * 1024 + n * 8 + (lq & 1) * 4)) = sp;
            }
        __syncthreads();
    }
}

// ---------------- K4: projection GEMM via MFMA + BN2 + residual -> d_out ----------------
__global__ __launch_bounds__(256) void k_proj_mfma(const _Float16* __restrict__ OsF,
                                                   const _Float16* __restrict__ WpH,
                                                   const float* __restrict__ g2,
                                                   const float* __restrict__ b2,
                                                   const float* __restrict__ m2,
                                                   const float* __restrict__ vv2,
                                                   const float* __restrict__ x,
                                                   float* __restrict__ out) {
    __shared__ __align__(16) _Float16 Bs[4][128][8];

    int nt = blockIdx.x;
    int ot = blockIdx.y;
    int tb = blockIdx.z;
    int tid = threadIdx.x;
    int wave = tid >> 6;
    int lane = tid & 63;
    int l16 = lane & 15, lq = lane >> 4;
    int wr = (wave & 1) * 64, wc = (wave >> 1) * 64;

    f32x4 acc[4][4];
#pragma unroll
    for (int i = 0; i < 4; i++)
#pragma unroll
        for (int j = 0; j < 4; j++) acc[i][j] = (f32x4){0.f, 0.f, 0.f, 0.f};

    for (int kb = 0; kb < 12; ++kb) {
        __syncthreads();
        const char* src = (const char*)(OsF + ((size_t)(tb * NHEAD + kb) * 8 + nt) * 4096);
#if USE_GLL
#pragma unroll
        for (int i = 0; i < 2; ++i) {
            int off = (tid + i * 256) * 16;
            load_lds16(src + off, (char*)&Bs[0][0][0] + off);
        }
#else
#pragma unroll
        for (int i = 0; i < 2; ++i) {
            int off = (tid + i * 256) * 16;
            *(float4*)((char*)&Bs[0][0][0] + off) = *(const float4*)(src + off);
        }
#endif
        const _Float16* wbase = WpH + (size_t)(kb * 3 + ot) * 4096 + lq * 1024;
        f16x8 af[4];
#pragma unroll
        for (int fi = 0; fi < 4; fi++)
            af[fi] = *(const f16x8*)(wbase + (size_t)(wr + fi * 16 + l16) * 8);
        __syncthreads();

        f16x8 bf[4];
#pragma unroll
        for (int fj = 0; fj < 4; fj++)
            bf[fj] = *(const f16x8*)&Bs[lq][wc + fj * 16 + l16][0];
#pragma unroll
        for (int fi = 0; fi < 4; fi++)
#pragma unroll
            for (int fj = 0; fj < 4; fj++)
                acc[fi][fj] = __builtin_amdgcn_mfma_f32_16x16x32_f16(af[fi], bf[fj], acc[fi][fj], 0, 0, 0);
    }

    size_t orow_base = (size_t)tb * CC * HWN;
    int n_base = nt * 128 + wc;
#pragma unroll
    for (int fi = 0; fi < 4; fi++) {
        float invv[4], muv[4], btv[4];
#pragma unroll
        for (int r = 0; r < 4; r++) {
            int o = ot * 128 + wr + fi * 16 + lq * 4 + r;
            invv[r] = g2[o] / sqrtf(vv2[o] + 1e-5f);
            muv[r] = m2[o];
            btv[r] = b2[o];
        }
#pragma unroll
        for (int fj = 0; fj < 4; fj++) {
#pragma unroll
            for (int r = 0; r < 4; r++) {
                int o = ot * 128 + wr + fi * 16 + lq * 4 + r;
                size_t addr = orow_base + (size_t)o * HWN + n_base + fj * 16 + l16;
                out[addr] = (acc[fi][fj][r] - muv[r]) * invv[r] + btv[r] + x[addr];
            }
        }
    }
}

extern "C" void kernel_launch(void* const* d_in, const int* in_sizes, int n_in,
                              void* d_out, int out_size, void* d_ws, size_t ws_size,
                              hipStream_t stream) {
    const float* x = (const float*)d_in[0];
    const float* w_conv = (const float*)d_in[1];
    const float* bn1_gamma = (const float*)d_in[2];
    const float* bn1_beta = (const float*)d_in[3];
    const float* bn1_mean = (const float*)d_in[4];
    const float* bn1_var = (const float*)d_in[5];
    const float* w_proj = (const float*)d_in[6];
    const float* bn2_gamma = (const float*)d_in[7];
    const float* bn2_beta = (const float*)d_in[8];
    const float* bn2_mean = (const float*)d_in[9];
    const float* bn2_var = (const float*)d_in[10];
    const float* fr_x = (const float*)d_in[11];
    const float* fr_attn = (const float*)d_in[12];

    // workspace layout
    const size_t SPIKE = (size_t)TT * BB * CC * HWN;              // 12,582,912 (u8 xs)
    const size_t FRAG = (size_t)TT * BB * NHEAD * 8 * 4096 * 2;   // 25,165,824 (xsF / OsF)
    const size_t AB = (size_t)TT * BB * NHEAD * 4096 * 2;         // 3,145,728 (A1 / A2)
    const size_t WB = (size_t)KCONV * C2 * 2;                     // 9,437,184
    const size_t WPB = (size_t)CC * CC * 2;                       // 294,912
    const size_t PB = (size_t)MROWS * C2 * 4;                     // 6,291,456 per split
    unsigned char* xs = (unsigned char*)d_ws;
    _Float16* xsF = (_Float16*)(xs + SPIKE);
    _Float16* OsF = (_Float16*)((char*)xsF + FRAG);
    _Float16* A1 = (_Float16*)((char*)OsF + FRAG);
    _Float16* A2 = (_Float16*)((char*)A1 + AB);
    _Float16* W0 = (_Float16*)((char*)A2 + AB);
    _Float16* W1 = (_Float16*)((char*)W0 + WB);
    _Float16* WpH = (_Float16*)((char*)W1 + WB);
    char* tail = (char*)WpH + WPB;

    int KS;
    float* P;
    if (ws_size >= (size_t)(tail - (char*)d_ws) + 8 * PB) {
        KS = 8;
        P = (float*)tail;
    } else if (ws_size >= (size_t)(tail - (char*)d_ws) + 4 * PB) {
        KS = 4;
        P = (float*)tail;
    } else {
        KS = 2;                    // alias P onto OsF region (OsF written later by k_attn)
        P = (float*)OsF;
    }
    int kbPerSplit = KB_TOT / KS;

    k_pack<<<(KCONV * C2 / 8) / 256, 256, 0, stream>>>(w_conv, W0, W1);
    k_pack_wp<<<(CC * CC / 8) / 256, 256, 0, stream>>>(w_proj, WpH);
    k_lif1<<<dim3(16, BB * NHEAD), 256, 0, stream>>>(x, xs, xsF);
    k_conv_mfma<<<dim3(16, 6, KS), 256, 0, stream>>>(xs, W0, W1, P, kbPerSplit);
    k_reduce_frag<<<32 * NHEAD, 256, 0, stream>>>(P, bn1_gamma, bn1_beta, bn1_mean, bn1_var, A1, A2, KS);
    k_attn_mfma<<<dim3(8, BB * NHEAD), 256, 0, stream>>>(xsF, A1, A2, fr_x, fr_attn, OsF);
    k_proj_mfma<<<dim3(8, 3, 32), 256, 0, stream>>>(OsF, WpH, bn2_gamma, bn2_beta, bn2_mean, bn2_var, x, (float*)d_out);
}

// Round 5
// 172.939 us; speedup vs baseline: 3.3849x; 1.0037x over previous
//
#include <hip/hip_runtime.h>
#include <math.h>

// Problem dims (fixed)
#define TT 4
#define BB 8
#define CC 384
#define HWN 1024      // 32*32
#define NHEAD 12
#define CHD 32        // C / heads
#define C2 768        // 2*C
#define LL 64         // 8*8 patches
#define KCONV 6144    // C*4*4
#define KB_TOT 192    // KCONV/32
#define MROWS 2048    // TT*BB*64

typedef _Float16 f16x8 __attribute__((ext_vector_type(8)));
typedef _Float16 f16x4 __attribute__((ext_vector_type(4)));
typedef float f32x4 __attribute__((ext_vector_type(4)));

#if defined(__has_builtin)
#if __has_builtin(__builtin_amdgcn_global_load_lds)
#define USE_GLL 1
#endif
#endif
#ifndef USE_GLL
#define USE_GLL 0
#endif

#if USE_GLL
typedef __attribute__((address_space(3))) unsigned int lds_uint;
typedef const __attribute__((address_space(1))) unsigned int glob_uint;
__device__ __forceinline__ void load_lds16(const void* g, void* l) {
    __builtin_amdgcn_global_load_lds((glob_uint*)g, (lds_uint*)l, 16, 0, 0);
}
#endif

// ---------------- K0: pack w_conv into fragment-major f16 hi/lo splits ----------------
// Layout: W[(kb*6+nb)*4096 + q*1024 + col*8 + j], k = kb*32 + q*8 + j, n = nb*128+col.
__global__ __launch_bounds__(256) void k_pack(const float* __restrict__ w,
                                              _Float16* __restrict__ W0,
                                              _Float16* __restrict__ W1) {
    int g = blockIdx.x * 256 + threadIdx.x;   // 0..589823
    int o = g * 8;
    int kbnb = o >> 12;                        // kb*6+nb
    int kb = kbnb / 6;
    int nb = kbnb - kb * 6;
    int q = (o >> 10) & 3;
    int col = (o >> 3) & 127;
    int k = kb * 32 + q * 8;
    int n = nb * 128 + col;
    const float* src = w + (size_t)n * KCONV + k;
    f16x8 h, l;
#pragma unroll
    for (int j = 0; j < 8; j++) {
        float wv = src[j];
        _Float16 hi = (_Float16)wv;
        float rem = (wv - (float)hi) * 2048.0f;
        h[j] = hi;
        l[j] = (_Float16)rem;
    }
    *(f16x8*)(W0 + o) = h;
    *(f16x8*)(W1 + o) = l;
}

// ---------------- K0b: pack w_proj [384][384] into A-fragment-major f16 ----------------
__global__ __launch_bounds__(256) void k_pack_wp(const float* __restrict__ wp,
                                                 _Float16* __restrict__ WpH) {
    int g = blockIdx.x * 256 + threadIdx.x;   // 0..18431
    int o8 = g * 8;
    int kbot = o8 >> 12;                       // 0..35
    int kb = kbot / 3;
    int ot = kbot - kb * 3;
    int q = (o8 >> 10) & 3;
    int row = (o8 >> 3) & 127;
    int o = ot * 128 + row;
    int c = kb * 32 + q * 8;
    const float* src = wp + (size_t)o * CC + c;
    f16x8 h;
#pragma unroll
    for (int j = 0; j < 8; j++) h[j] = (_Float16)src[j];
    *(f16x8*)(WpH + o8) = h;
}

// ---------------- K1: LIF over T on x -> xsC (conv A-frags f16) + xsF (attn B-frags f16) ----------------
// xsC region (mt,kb): [q=4][row=128][j=8] halfs; m = mt*128+row = tb*64+pp; k = kb*32+q*8+j.
// xsF region (tb,hh,nt): [q=4][n=128][j=8]; d = q*8+j.
// grid dim3(16, 96): x = q8*4 + nt256, y = b*12 + hh.
__global__ __launch_bounds__(256) void k_lif1(const float* __restrict__ x,
                                              _Float16* __restrict__ xsC,
                                              _Float16* __restrict__ xsF) {
    int nt = blockIdx.x & 3, q8 = blockIdx.x >> 2;
    int bh = blockIdx.y;
    int b = bh / NHEAD, hh = bh % NHEAD;
    int n = nt * 256 + threadIdx.x;
    const int stride = BB * CC * HWN;
    int h = n >> 5, w = n & 31;
    int pi = h >> 2, a = h & 3, pj = w >> 2, bp = w & 3;
    int rowp = pi * 8 + pj;
    int qa = a >> 1;
    int jc = (a & 1) * 4 + bp;
    size_t base0 = ((size_t)b * CC + hh * 32 + q8 * 8) * HWN + n;
    f16x8 frag[4];
#pragma unroll
    for (int j = 0; j < 8; j++) {
        int c = hh * 32 + q8 * 8 + j;
        int kb = c >> 1;
        int qc = (c & 1) * 2 + qa;
        size_t cbase = (size_t)kb * 4096 + qc * 1024 + jc;
        float v = 0.0f;
        size_t off = base0 + (size_t)j * HWN;
#pragma unroll
        for (int t = 0; t < TT; t++) {
            float xv = x[(size_t)t * stride + off];
            v += (xv - v) * 0.5f;
            float s = (v >= 1.0f) ? 1.0f : 0.0f;
            if (s > 0.0f) v = 0.0f;
            frag[t][j] = (_Float16)s;
            int tb = t * BB + b;
            int mt = tb >> 1;
            int row = (tb & 1) * 64 + rowp;
            xsC[(size_t)mt * (192 * 4096) + cbase + (size_t)row * 8] = (_Float16)s;
        }
    }
#pragma unroll
    for (int t = 0; t < TT; t++) {
        int tb = t * BB + b;
        size_t dst = ((size_t)(tb * NHEAD + hh) * 8 + (n >> 7)) * 4096 + q8 * 1024 + (size_t)(n & 127) * 8;
        *(f16x8*)(xsF + dst) = frag[t];
    }
}

// ---------------- K2: conv-as-GEMM via f16 MFMA (hi/lo split), split-K partials ----------------
// grid (16 mtiles, 6 ntiles, KS). block 256 = 4 waves, each wave 64x64.
// All staging is linear global_load_lds from pre-packed fragment buffers.
__global__ __launch_bounds__(256) void k_conv_mfma(const _Float16* __restrict__ xsC,
                                                   const _Float16* __restrict__ W0,
                                                   const _Float16* __restrict__ W1,
                                                   float* __restrict__ P,
                                                   int kbPerSplit) {
    __shared__ __align__(16) _Float16 As[4096];   // 8 KB  [q][row][j]
    __shared__ __align__(16) _Float16 Bh[4096];   // 8 KB  [q][col][j]
    __shared__ __align__(16) _Float16 Bl[4096];   // 8 KB

    int mt = blockIdx.x;
    int nt = blockIdx.y;
    int s = blockIdx.z;
    int kb0 = s * kbPerSplit;
    int tid = threadIdx.x;
    int wave = tid >> 6;
    int lane = tid & 63;
    int l16 = lane & 15, lq = lane >> 4;
    int wr = (wave & 1) * 64, wc = (wave >> 1) * 64;

    f32x4 acc0[4][4], acc1[4][4];
#pragma unroll
    for (int i = 0; i < 4; i++)
#pragma unroll
        for (int j = 0; j < 4; j++) {
            acc0[i][j] = (f32x4){0.f, 0.f, 0.f, 0.f};
            acc1[i][j] = (f32x4){0.f, 0.f, 0.f, 0.f};
        }

    const char* aBase = (const char*)xsC + (size_t)mt * (192 * 8192);
    const char* b0Base = (const char*)W0 + (size_t)nt * 8192;
    const char* b1Base = (const char*)W1 + (size_t)nt * 8192;
    int wo = wave * 2048;

    for (int kb = kb0; kb < kb0 + kbPerSplit; ++kb) {
        __syncthreads();
        const char* aSrc = aBase + (size_t)kb * 8192;
        const char* b0Src = b0Base + (size_t)kb * (6 * 8192);
        const char* b1Src = b1Base + (size_t)kb * (6 * 8192);
#if USE_GLL
        load_lds16(aSrc + wo + lane * 16, (char*)As + wo);
        load_lds16(aSrc + wo + 1024 + lane * 16, (char*)As + wo + 1024);
        load_lds16(b0Src + wo + lane * 16, (char*)Bh + wo);
        load_lds16(b0Src + wo + 1024 + lane * 16, (char*)Bh + wo + 1024);
        load_lds16(b1Src + wo + lane * 16, (char*)Bl + wo);
        load_lds16(b1Src + wo + 1024 + lane * 16, (char*)Bl + wo + 1024);
#else
#pragma unroll
        for (int i = 0; i < 2; ++i) {
            int off = wo + i * 1024 + lane * 16;
            *(float4*)((char*)As + off) = *(const float4*)(aSrc + off);
            *(float4*)((char*)Bh + off) = *(const float4*)(b0Src + off);
            *(float4*)((char*)Bl + off) = *(const float4*)(b1Src + off);
        }
#endif
        __syncthreads();

        f16x8 af[4];
#pragma unroll
        for (int fi = 0; fi < 4; fi++)
            af[fi] = *(const f16x8*)&As[(size_t)(lq * 128 + wr + fi * 16 + l16) * 8];
        f16x8 bf[4];
#pragma unroll
        for (int fj = 0; fj < 4; fj++)
            bf[fj] = *(const f16x8*)&Bh[(size_t)(lq * 128 + wc + fj * 16 + l16) * 8];
#pragma unroll
        for (int fi = 0; fi < 4; fi++)
#pragma unroll
            for (int fj = 0; fj < 4; fj++)
                acc0[fi][fj] = __builtin_amdgcn_mfma_f32_16x16x32_f16(af[fi], bf[fj], acc0[fi][fj], 0, 0, 0);
#pragma unroll
        for (int fj = 0; fj < 4; fj++)
            bf[fj] = *(const f16x8*)&Bl[(size_t)(lq * 128 + wc + fj * 16 + l16) * 8];
#pragma unroll
        for (int fi = 0; fi < 4; fi++)
#pragma unroll
            for (int fj = 0; fj < 4; fj++)
                acc1[fi][fj] = __builtin_amdgcn_mfma_f32_16x16x32_f16(af[fi], bf[fj], acc1[fi][fj], 0, 0, 0);
    }

    size_t Pbase = (size_t)s * MROWS * C2;
#pragma unroll
    for (int fi = 0; fi < 4; fi++)
#pragma unroll
        for (int fj = 0; fj < 4; fj++) {
            int ccol = nt * 128 + wc + fj * 16 + l16;
#pragma unroll
            for (int r = 0; r < 4; r++) {
                int rr = mt * 128 + wr + fi * 16 + lq * 4 + r;
                float v = acc0[fi][fj][r] + acc1[fi][fj][r] * (1.0f / 2048.0f);
                P[Pbase + (size_t)rr * C2 + ccol] = v;
            }
        }
}

// ---------------- K2b: reduce split-K + BN1 -> A1/A2 hi-lo f16 fragments per (tb,hh) ----------------
__global__ __launch_bounds__(256) void k_reduce_frag(const float* __restrict__ P,
                                                     const float* __restrict__ g1,
                                                     const float* __restrict__ b1,
                                                     const float* __restrict__ m1,
                                                     const float* __restrict__ v1,
                                                     _Float16* __restrict__ A1,
                                                     _Float16* __restrict__ A2,
                                                     int KS) {
    __shared__ float y2ls[32][66];
    int tb = blockIdx.x / NHEAD, hh = blockIdx.x % NHEAD;
    int tid = threadIdx.x;
    int pp = tid >> 2, cq = (tid & 3) * 16;

    size_t rowbase = ((size_t)tb * 64 + pp) * C2 + hh * 64 + cq;
    float yv[16];
#pragma unroll
    for (int i = 0; i < 16; i++) yv[i] = 0.0f;
    for (int s = 0; s < KS; s++) {
        const float* p = P + (size_t)s * MROWS * C2 + rowbase;
#pragma unroll
        for (int i4 = 0; i4 < 4; i4++) {
            float4 v = *(const float4*)(p + i4 * 4);
            yv[i4 * 4 + 0] += v.x;
            yv[i4 * 4 + 1] += v.y;
            yv[i4 * 4 + 2] += v.z;
            yv[i4 * 4 + 3] += v.w;
        }
    }
#pragma unroll
    for (int i = 0; i < 16; i++) {
        int oc = hh * 64 + cq + i;
        float inv = g1[oc] / sqrtf(v1[oc] + 1e-5f);
        yv[i] = (yv[i] - m1[oc]) * inv + b1[oc];
    }

    size_t reg = (size_t)(tb * NHEAD + hh) * 4096;
    if (cq < 32) {
#pragma unroll
        for (int gi = 0; gi < 2; gi++) {
            int c0 = cq + gi * 8;
            f16x8 h, l;
#pragma unroll
            for (int j = 0; j < 8; j++) {
                float v = yv[gi * 8 + j];
                _Float16 hi = (_Float16)v;
                h[j] = hi;
                l[j] = (_Float16)((v - (float)hi) * 2048.0f);
            }
            size_t a = reg + (size_t)(((pp >> 4) * 4 + (c0 >> 3)) * 128 + (pp & 15) * 8);
            *(f16x8*)(A1 + a) = h;
            *(f16x8*)(A1 + a + 2048) = l;
        }
    } else {
#pragma unroll
        for (int i = 0; i < 16; i++) y2ls[cq - 32 + i][pp] = yv[i];
    }
    __syncthreads();
    int d16 = tid & 15, grp = tid >> 4;
    f16x8 h, l;
#pragma unroll
    for (int j = 0; j < 8; j++) {
        float v = y2ls[(grp >> 3) * 16 + d16][((grp >> 2) & 1) * 32 + (grp & 3) * 8 + j];
        _Float16 hi = (_Float16)v;
        h[j] = hi;
        l[j] = (_Float16)((v - (float)hi) * 2048.0f);
    }
    size_t a = reg + (size_t)((grp * 16 + d16) * 8);
    *(f16x8*)(A2 + a) = h;
    *(f16x8*)(A2 + a + 2048) = l;
}

// ---------------- K3: fused attention via MFMA -> OsF ----------------
__global__ __launch_bounds__(256) void k_attn_mfma(const _Float16* __restrict__ xsF,
                                                   const _Float16* __restrict__ A1,
                                                   const _Float16* __restrict__ A2,
                                                   const float* __restrict__ fr_x,
                                                   const float* __restrict__ fr_attn,
                                                   _Float16* __restrict__ OsF) {
    __shared__ __align__(16) _Float16 Bs[4][128][8];    // 8 KB xr tile
    __shared__ __align__(16) _Float16 Sat[8][128][8];   // 16 KB attn spikes

    int nt = blockIdx.x;
    int bh = blockIdx.y;
    int b = bh / NHEAD, hh = bh % NHEAD;
    int tid = threadIdx.x;
    int w = tid >> 6;
    int lane = tid & 63;
    int l16 = lane & 15, lq = lane >> 4;

    float scale1 = 1.0f / sqrtf(fr_x[hh] * 32.0f);
    float scale2 = 1.0f / sqrtf(fr_attn[hh] * 64.0f);

    float va[8][4];
    float vo[2][2][4];
#pragma unroll
    for (int nf = 0; nf < 8; nf++)
#pragma unroll
        for (int r = 0; r < 4; r++) va[nf][r] = 0.0f;
#pragma unroll
    for (int dt = 0; dt < 2; dt++)
#pragma unroll
        for (int nf = 0; nf < 2; nf++)
#pragma unroll
            for (int r = 0; r < 4; r++) vo[dt][nf][r] = 0.0f;

    for (int t = 0; t < TT; t++) {
        int tb = t * BB + b;
        size_t reg = (size_t)(tb * NHEAD + hh);
        const char* src = (const char*)(xsF + (reg * 8 + nt) * 4096);
#if USE_GLL
        load_lds16(src + tid * 16, (char*)&Bs[0][0][0] + tid * 16);
        load_lds16(src + tid * 16 + 4096, (char*)&Bs[0][0][0] + tid * 16 + 4096);
#else
        *(float4*)((char*)&Bs[0][0][0] + tid * 16) = *(const float4*)(src + tid * 16);
        *(float4*)((char*)&Bs[0][0][0] + tid * 16 + 4096) = *(const float4*)(src + tid * 16 + 4096);
#endif
        const _Float16* a1b = A1 + reg * 4096;
        f16x8 a1h = *(const f16x8*)(a1b + (size_t)(((w * 4 + lq) * 16 + l16) * 8));
        f16x8 a1l = *(const f16x8*)(a1b + 2048 + (size_t)(((w * 4 + lq) * 16 + l16) * 8));
        __syncthreads();

        f32x4 ah[8], al[8];
#pragma unroll
        for (int nf = 0; nf < 8; nf++) {
            ah[nf] = (f32x4){0.f, 0.f, 0.f, 0.f};
            al[nf] = (f32x4){0.f, 0.f, 0.f, 0.f};
        }
#pragma unroll
        for (int nf = 0; nf < 8; nf++) {
            f16x8 bf = *(const f16x8*)&Bs[lq][nf * 16 + l16][0];
            ah[nf] = __builtin_amdgcn_mfma_f32_16x16x32_f16(a1h, bf, ah[nf], 0, 0, 0);
            al[nf] = __builtin_amdgcn_mfma_f32_16x16x32_f16(a1l, bf, al[nf], 0, 0, 0);
        }
        int pq = w * 2 + (lq >> 1);
#pragma unroll
        for (int nf = 0; nf < 8; nf++) {
            f16x4 sp;
#pragma unroll
            for (int r = 0; r < 4; r++) {
                float a = (ah[nf][r] + al[nf][r] * (1.0f / 2048.0f)) * scale1;
                float v = va[nf][r];
                v += (a - v) * 0.5f;
                float s = (v >= 1.0f) ? 1.0f : 0.0f;
                va[nf][r] = (s > 0.0f) ? 0.0f : v;
                sp[r] = (_Float16)s;
            }
            *(f16x4*)&Sat[pq][nf * 16 + l16][(lq & 1) * 4] = sp;
        }
        __syncthreads();

        const _Float16* a2b = A2 + reg * 4096;
        f32x4 oh[2][2], ol[2][2];
#pragma unroll
        for (int dt = 0; dt < 2; dt++)
#pragma unroll
            for (int nf = 0; nf < 2; nf++) {
                oh[dt][nf] = (f32x4){0.f, 0.f, 0.f, 0.f};
                ol[dt][nf] = (f32x4){0.f, 0.f, 0.f, 0.f};
            }
#pragma unroll
        for (int ks = 0; ks < 2; ks++) {
            f16x8 bf0 = *(const f16x8*)&Sat[ks * 4 + lq][w * 32 + l16][0];
            f16x8 bf1 = *(const f16x8*)&Sat[ks * 4 + lq][w * 32 + 16 + l16][0];
#pragma unroll
            for (int dt = 0; dt < 2; dt++) {
                size_t ao = (size_t)(((dt * 8 + ks * 4 + lq) * 16 + l16) * 8);
                f16x8 a2h = *(const f16x8*)(a2b + ao);
                f16x8 a2l = *(const f16x8*)(a2b + 2048 + ao);
                oh[dt][0] = __builtin_amdgcn_mfma_f32_16x16x32_f16(a2h, bf0, oh[dt][0], 0, 0, 0);
                ol[dt][0] = __builtin_amdgcn_mfma_f32_16x16x32_f16(a2l, bf0, ol[dt][0], 0, 0, 0);
                oh[dt][1] = __builtin_amdgcn_mfma_f32_16x16x32_f16(a2h, bf1, oh[dt][1], 0, 0, 0);
                ol[dt][1] = __builtin_amdgcn_mfma_f32_16x16x32_f16(a2l, bf1, ol[dt][1], 0, 0, 0);
            }
        }
        _Float16* og = OsF + (reg * 8 + nt) * 4096;
#pragma unroll
        for (int dt = 0; dt < 2; dt++)
#pragma unroll
            for (int nf = 0; nf < 2; nf++) {
                f16x4 sp;
#pragma unroll
                for (int r = 0; r < 4; r++) {
                    float a = (oh[dt][nf][r] + ol[dt][nf][r] * (1.0f / 2048.0f)) * scale2;
                    float v = vo[dt][nf][r];
                    v += (a - v) * 0.5f;
                    float s = (v >= 1.0f) ? 1.0f : 0.0f;
                    vo[dt][nf][r] = (s > 0.0f) ? 0.0f : v;
                    sp[r] = (_Float16)s;
                }
                int n = w * 32 + nf * 16 + l16;
                *(f16x4*)(og + (size_t)((dt * 2 + (lq >> 1)) * 1024 + n * 8 + (lq & 1) * 4)) = sp;
            }
        __syncthreads();
    }
}

// ---------------- K4: projection GEMM via MFMA + BN2 + residual -> d_out ----------------
__global__ __launch_bounds__(256) void k_proj_mfma(const _Float16* __restrict__ OsF,
                                                   const _Float16* __restrict__ WpH,
                                                   const float* __restrict__ g2,
                                                   const float* __restrict__ b2,
                                                   const float* __restrict__ m2,
                                                   const float* __restrict__ vv2,
                                                   const float* __restrict__ x,
                                                   float* __restrict__ out) {
    __shared__ __align__(16) _Float16 Bs[4][128][8];

    int nt = blockIdx.x;
    int ot = blockIdx.y;
    int tb = blockIdx.z;
    int tid = threadIdx.x;
    int wave = tid >> 6;
    int lane = tid & 63;
    int l16 = lane & 15, lq = lane >> 4;
    int wr = (wave & 1) * 64, wc = (wave >> 1) * 64;

    f32x4 acc[4][4];
#pragma unroll
    for (int i = 0; i < 4; i++)
#pragma unroll
        for (int j = 0; j < 4; j++) acc[i][j] = (f32x4){0.f, 0.f, 0.f, 0.f};

    for (int kb = 0; kb < 12; ++kb) {
        __syncthreads();
        const char* src = (const char*)(OsF + ((size_t)(tb * NHEAD + kb) * 8 + nt) * 4096);
#if USE_GLL
#pragma unroll
        for (int i = 0; i < 2; ++i) {
            int off = (tid + i * 256) * 16;
            load_lds16(src + off, (char*)&Bs[0][0][0] + off);
        }
#else
#pragma unroll
        for (int i = 0; i < 2; ++i) {
            int off = (tid + i * 256) * 16;
            *(float4*)((char*)&Bs[0][0][0] + off) = *(const float4*)(src + off);
        }
#endif
        const _Float16* wbase = WpH + (size_t)(kb * 3 + ot) * 4096 + lq * 1024;
        f16x8 af[4];
#pragma unroll
        for (int fi = 0; fi < 4; fi++)
            af[fi] = *(const f16x8*)(wbase + (size_t)(wr + fi * 16 + l16) * 8);
        __syncthreads();

        f16x8 bf[4];
#pragma unroll
        for (int fj = 0; fj < 4; fj++)
            bf[fj] = *(const f16x8*)&Bs[lq][wc + fj * 16 + l16][0];
#pragma unroll
        for (int fi = 0; fi < 4; fi++)
#pragma unroll
            for (int fj = 0; fj < 4; fj++)
                acc[fi][fj] = __builtin_amdgcn_mfma_f32_16x16x32_f16(af[fi], bf[fj], acc[fi][fj], 0, 0, 0);
    }

    size_t orow_base = (size_t)tb * CC * HWN;
    int n_base = nt * 128 + wc;
#pragma unroll
    for (int fi = 0; fi < 4; fi++) {
        float invv[4], muv[4], btv[4];
#pragma unroll
        for (int r = 0; r < 4; r++) {
            int o = ot * 128 + wr + fi * 16 + lq * 4 + r;
            invv[r] = g2[o] / sqrtf(vv2[o] + 1e-5f);
            muv[r] = m2[o];
            btv[r] = b2[o];
        }
#pragma unroll
        for (int fj = 0; fj < 4; fj++) {
#pragma unroll
            for (int r = 0; r < 4; r++) {
                int o = ot * 128 + wr + fi * 16 + lq * 4 + r;
                size_t addr = orow_base + (size_t)o * HWN + n_base + fj * 16 + l16;
                out[addr] = (acc[fi][fj][r] - muv[r]) * invv[r] + btv[r] + x[addr];
            }
        }
    }
}

extern "C" void kernel_launch(void* const* d_in, const int* in_sizes, int n_in,
                              void* d_out, int out_size, void* d_ws, size_t ws_size,
                              hipStream_t stream) {
    const float* x = (const float*)d_in[0];
    const float* w_conv = (const float*)d_in[1];
    const float* bn1_gamma = (const float*)d_in[2];
    const float* bn1_beta = (const float*)d_in[3];
    const float* bn1_mean = (const float*)d_in[4];
    const float* bn1_var = (const float*)d_in[5];
    const float* w_proj = (const float*)d_in[6];
    const float* bn2_gamma = (const float*)d_in[7];
    const float* bn2_beta = (const float*)d_in[8];
    const float* bn2_mean = (const float*)d_in[9];
    const float* bn2_var = (const float*)d_in[10];
    const float* fr_x = (const float*)d_in[11];
    const float* fr_attn = (const float*)d_in[12];

    // workspace layout
    const size_t FRAG = (size_t)16 * 192 * 4096 * 2;              // 25,165,824 (xsC; also xsF/OsF size)
    const size_t AB = (size_t)TT * BB * NHEAD * 4096 * 2;         // 3,145,728 (A1 / A2)
    const size_t WB = (size_t)KCONV * C2 * 2;                     // 9,437,184
    const size_t WPB = (size_t)CC * CC * 2;                       // 294,912
    const size_t PB = (size_t)MROWS * C2 * 4;                     // 6,291,456 per split
    _Float16* xsC = (_Float16*)d_ws;
    _Float16* xsF = (_Float16*)((char*)xsC + FRAG);
    _Float16* OsF = (_Float16*)((char*)xsF + FRAG);
    _Float16* A1 = (_Float16*)((char*)OsF + FRAG);
    _Float16* A2 = (_Float16*)((char*)A1 + AB);
    _Float16* W0 = (_Float16*)((char*)A2 + AB);
    _Float16* W1 = (_Float16*)((char*)W0 + WB);
    _Float16* WpH = (_Float16*)((char*)W1 + WB);
    char* tail = (char*)WpH + WPB;

    int KS;
    float* P;
    if (ws_size >= (size_t)(tail - (char*)d_ws) + 8 * PB) {
        KS = 8;
        P = (float*)tail;
    } else if (ws_size >= (size_t)(tail - (char*)d_ws) + 4 * PB) {
        KS = 4;
        P = (float*)tail;
    } else {
        KS = 2;                    // alias P onto OsF region (OsF written later by k_attn)
        P = (float*)OsF;
    }
    int kbPerSplit = KB_TOT / KS;

    k_pack<<<(KCONV * C2 / 8) / 256, 256, 0, stream>>>(w_conv, W0, W1);
    k_pack_wp<<<(CC * CC / 8) / 256, 256, 0, stream>>>(w_proj, WpH);
    k_lif1<<<dim3(16, BB * NHEAD), 256, 0, stream>>>(x, xsC, xsF);
    k_conv_mfma<<<dim3(16, 6, KS), 256, 0, stream>>>(xsC, W0, W1, P, kbPerSplit);
    k_reduce_frag<<<32 * NHEAD, 256, 0, stream>>>(P, bn1_gamma, bn1_beta, bn1_mean, bn1_var, A1, A2, KS);
    k_attn_mfma<<<dim3(8, BB * NHEAD), 256, 0, stream>>>(xsF, A1, A2, fr_x, fr_attn, OsF);
    k_proj_mfma<<<dim3(8, 3, 32), 256, 0, stream>>>(OsF, WpH, bn2_gamma, bn2_beta, bn2_mean, bn2_var, x, (float*)d_out);
}

// Round 6
// 146.813 us; speedup vs baseline: 3.9873x; 1.1780x over previous
//
#include <hip/hip_runtime.h>
#include <math.h>

// Problem dims (fixed)
#define TT 4
#define BB 8
#define CC 384
#define HWN 1024      // 32*32
#define NHEAD 12
#define CHD 32        // C / heads
#define C2 768        // 2*C
#define LL 64         // 8*8 patches
#define KCONV 6144    // C*4*4
#define KB_TOT 192    // KCONV/32
#define MROWS 2048    // TT*BB*64

typedef _Float16 f16x8 __attribute__((ext_vector_type(8)));
typedef _Float16 f16x4 __attribute__((ext_vector_type(4)));
typedef float f32x4 __attribute__((ext_vector_type(4)));

#if defined(__has_builtin)
#if __has_builtin(__builtin_amdgcn_global_load_lds)
#define USE_GLL 1
#endif
#endif
#ifndef USE_GLL
#define USE_GLL 0
#endif

#if USE_GLL
typedef __attribute__((address_space(3))) unsigned int lds_uint;
typedef const __attribute__((address_space(1))) unsigned int glob_uint;
__device__ __forceinline__ void load_lds16(const void* g, void* l) {
    __builtin_amdgcn_global_load_lds((glob_uint*)g, (lds_uint*)l, 16, 0, 0);
}
#endif

// ---------------- K0: pack w_conv into fragment-major f16 hi/lo splits ----------------
// Layout: W[(kb*6+nb)*4096 + q*1024 + col*8 + j], k = kb*32 + q*8 + j, n = nb*128+col.
__global__ __launch_bounds__(256) void k_pack(const float* __restrict__ w,
                                              _Float16* __restrict__ W0,
                                              _Float16* __restrict__ W1) {
    int g = blockIdx.x * 256 + threadIdx.x;   // 0..589823
    int o = g * 8;
    int kbnb = o >> 12;                        // kb*6+nb
    int kb = kbnb / 6;
    int nb = kbnb - kb * 6;
    int q = (o >> 10) & 3;
    int col = (o >> 3) & 127;
    int k = kb * 32 + q * 8;
    int n = nb * 128 + col;
    const float* src = w + (size_t)n * KCONV + k;
    f16x8 h, l;
#pragma unroll
    for (int j = 0; j < 8; j++) {
        float wv = src[j];
        _Float16 hi = (_Float16)wv;
        float rem = (wv - (float)hi) * 2048.0f;
        h[j] = hi;
        l[j] = (_Float16)rem;
    }
    *(f16x8*)(W0 + o) = h;
    *(f16x8*)(W1 + o) = l;
}

// ---------------- K0b: pack w_proj [384][384] into A-fragment-major f16 ----------------
__global__ __launch_bounds__(256) void k_pack_wp(const float* __restrict__ wp,
                                                 _Float16* __restrict__ WpH) {
    int g = blockIdx.x * 256 + threadIdx.x;   // 0..18431
    int o8 = g * 8;
    int kbot = o8 >> 12;                       // 0..35
    int kb = kbot / 3;
    int ot = kbot - kb * 3;
    int q = (o8 >> 10) & 3;
    int row = (o8 >> 3) & 127;
    int o = ot * 128 + row;
    int c = kb * 32 + q * 8;
    const float* src = wp + (size_t)o * CC + c;
    f16x8 h;
#pragma unroll
    for (int j = 0; j < 8; j++) h[j] = (_Float16)src[j];
    *(f16x8*)(WpH + o8) = h;
}

// ---------------- K1: LIF over T on x -> xsC (conv A-frags f16) + xsF (attn B-frags f16) ----------------
__global__ __launch_bounds__(256) void k_lif1(const float* __restrict__ x,
                                              _Float16* __restrict__ xsC,
                                              _Float16* __restrict__ xsF) {
    int nt = blockIdx.x & 3, q8 = blockIdx.x >> 2;
    int bh = blockIdx.y;
    int b = bh / NHEAD, hh = bh % NHEAD;
    int n = nt * 256 + threadIdx.x;
    const int stride = BB * CC * HWN;
    int h = n >> 5, w = n & 31;
    int pi = h >> 2, a = h & 3, pj = w >> 2, bp = w & 3;
    int rowp = pi * 8 + pj;
    int qa = a >> 1;
    int jc = (a & 1) * 4 + bp;
    size_t base0 = ((size_t)b * CC + hh * 32 + q8 * 8) * HWN + n;
    f16x8 frag[4];
#pragma unroll
    for (int j = 0; j < 8; j++) {
        int c = hh * 32 + q8 * 8 + j;
        int kb = c >> 1;
        int qc = (c & 1) * 2 + qa;
        size_t cbase = (size_t)kb * 4096 + qc * 1024 + jc;
        float v = 0.0f;
        size_t off = base0 + (size_t)j * HWN;
#pragma unroll
        for (int t = 0; t < TT; t++) {
            float xv = x[(size_t)t * stride + off];
            v += (xv - v) * 0.5f;
            float s = (v >= 1.0f) ? 1.0f : 0.0f;
            if (s > 0.0f) v = 0.0f;
            frag[t][j] = (_Float16)s;
            int tb = t * BB + b;
            int mt = tb >> 1;
            int row = (tb & 1) * 64 + rowp;
            xsC[(size_t)mt * (192 * 4096) + cbase + (size_t)row * 8] = (_Float16)s;
        }
    }
#pragma unroll
    for (int t = 0; t < TT; t++) {
        int tb = t * BB + b;
        size_t dst = ((size_t)(tb * NHEAD + hh) * 8 + (n >> 7)) * 4096 + q8 * 1024 + (size_t)(n & 127) * 8;
        *(f16x8*)(xsF + dst) = frag[t];
    }
}

// ---------------- K2: conv-as-GEMM via f16 MFMA (hi/lo split), split-K partials ----------------
// grid (16 mtiles, 6 ntiles, KS). block 256 = 4 waves, each wave 64x64.
// Double-buffered LDS; next tile staged (global_load_lds) while current computes.
// __launch_bounds__(256,2): cap VGPR+AGPR <= 256 -> 2 waves/SIMD (acc = 128 AGPR).
__global__ __launch_bounds__(256, 2) void k_conv_mfma(const _Float16* __restrict__ xsC,
                                                      const _Float16* __restrict__ W0,
                                                      const _Float16* __restrict__ W1,
                                                      float* __restrict__ P,
                                                      int kbPerSplit) {
    __shared__ __align__(16) _Float16 As[2][4096];   // 16 KB
    __shared__ __align__(16) _Float16 Bh[2][4096];   // 16 KB
    __shared__ __align__(16) _Float16 Bl[2][4096];   // 16 KB

    int mt = blockIdx.x;
    int nt = blockIdx.y;
    int s = blockIdx.z;
    int kb0 = s * kbPerSplit;
    int tid = threadIdx.x;
    int wave = tid >> 6;
    int lane = tid & 63;
    int l16 = lane & 15, lq = lane >> 4;
    int wr = (wave & 1) * 64, wc = (wave >> 1) * 64;

    f32x4 acc0[4][4], acc1[4][4];
#pragma unroll
    for (int i = 0; i < 4; i++)
#pragma unroll
        for (int j = 0; j < 4; j++) {
            acc0[i][j] = (f32x4){0.f, 0.f, 0.f, 0.f};
            acc1[i][j] = (f32x4){0.f, 0.f, 0.f, 0.f};
        }

    const char* aBase = (const char*)xsC + (size_t)mt * (192 * 8192);
    const char* b0Base = (const char*)W0 + (size_t)nt * 8192;
    const char* b1Base = (const char*)W1 + (size_t)nt * 8192;
    int wo = wave * 2048;
    int lo16 = lane * 16;

#if USE_GLL
#define STAGE(buf, kb) do {                                              \
    const char* aS = aBase + (size_t)(kb) * 8192;                        \
    const char* b0S = b0Base + (size_t)(kb) * (6 * 8192);                \
    const char* b1S = b1Base + (size_t)(kb) * (6 * 8192);                \
    load_lds16(aS + wo + lo16, (char*)As[buf] + wo);                     \
    load_lds16(aS + wo + 1024 + lo16, (char*)As[buf] + wo + 1024);       \
    load_lds16(b0S + wo + lo16, (char*)Bh[buf] + wo);                    \
    load_lds16(b0S + wo + 1024 + lo16, (char*)Bh[buf] + wo + 1024);      \
    load_lds16(b1S + wo + lo16, (char*)Bl[buf] + wo);                    \
    load_lds16(b1S + wo + 1024 + lo16, (char*)Bl[buf] + wo + 1024);      \
} while (0)
#else
#define STAGE(buf, kb) do {                                              \
    const char* aS = aBase + (size_t)(kb) * 8192;                        \
    const char* b0S = b0Base + (size_t)(kb) * (6 * 8192);                \
    const char* b1S = b1Base + (size_t)(kb) * (6 * 8192);                \
    _Pragma("unroll")                                                    \
    for (int i_ = 0; i_ < 2; ++i_) {                                     \
        int off_ = wo + i_ * 1024 + lo16;                                \
        *(float4*)((char*)As[buf] + off_) = *(const float4*)(aS + off_); \
        *(float4*)((char*)Bh[buf] + off_) = *(const float4*)(b0S + off_);\
        *(float4*)((char*)Bl[buf] + off_) = *(const float4*)(b1S + off_);\
    }                                                                    \
} while (0)
#endif

    STAGE(0, kb0);
    __syncthreads();

    int cur = 0;
    for (int i = 0; i < kbPerSplit; ++i) {
        if (i + 1 < kbPerSplit) STAGE(cur ^ 1, kb0 + i + 1);

        f16x8 af[4], bf[4];
#pragma unroll
        for (int fi = 0; fi < 4; fi++)
            af[fi] = *(const f16x8*)&As[cur][(size_t)(lq * 128 + wr + fi * 16 + l16) * 8];
#pragma unroll
        for (int fj = 0; fj < 4; fj++)
            bf[fj] = *(const f16x8*)&Bh[cur][(size_t)(lq * 128 + wc + fj * 16 + l16) * 8];
#pragma unroll
        for (int fi = 0; fi < 4; fi++)
#pragma unroll
            for (int fj = 0; fj < 4; fj++)
                acc0[fi][fj] = __builtin_amdgcn_mfma_f32_16x16x32_f16(af[fi], bf[fj], acc0[fi][fj], 0, 0, 0);
#pragma unroll
        for (int fj = 0; fj < 4; fj++)
            bf[fj] = *(const f16x8*)&Bl[cur][(size_t)(lq * 128 + wc + fj * 16 + l16) * 8];
#pragma unroll
        for (int fi = 0; fi < 4; fi++)
#pragma unroll
            for (int fj = 0; fj < 4; fj++)
                acc1[fi][fj] = __builtin_amdgcn_mfma_f32_16x16x32_f16(af[fi], bf[fj], acc1[fi][fj], 0, 0, 0);

        __syncthreads();
        cur ^= 1;
    }
#undef STAGE

    size_t Pbase = (size_t)s * MROWS * C2;
#pragma unroll
    for (int fi = 0; fi < 4; fi++)
#pragma unroll
        for (int fj = 0; fj < 4; fj++) {
            int ccol = nt * 128 + wc + fj * 16 + l16;
#pragma unroll
            for (int r = 0; r < 4; r++) {
                int rr = mt * 128 + wr + fi * 16 + lq * 4 + r;
                float v = acc0[fi][fj][r] + acc1[fi][fj][r] * (1.0f / 2048.0f);
                P[Pbase + (size_t)rr * C2 + ccol] = v;
            }
        }
}

// ---------------- K2b: reduce split-K + BN1 -> A1/A2 hi-lo f16 fragments per (tb,hh) ----------------
__global__ __launch_bounds__(256) void k_reduce_frag(const float* __restrict__ P,
                                                     const float* __restrict__ g1,
                                                     const float* __restrict__ b1,
                                                     const float* __restrict__ m1,
                                                     const float* __restrict__ v1,
                                                     _Float16* __restrict__ A1,
                                                     _Float16* __restrict__ A2,
                                                     int KS) {
    __shared__ float y2ls[32][66];
    int tb = blockIdx.x / NHEAD, hh = blockIdx.x % NHEAD;
    int tid = threadIdx.x;
    int pp = tid >> 2, cq = (tid & 3) * 16;

    size_t rowbase = ((size_t)tb * 64 + pp) * C2 + hh * 64 + cq;
    float yv[16];
#pragma unroll
    for (int i = 0; i < 16; i++) yv[i] = 0.0f;
    for (int s = 0; s < KS; s++) {
        const float* p = P + (size_t)s * MROWS * C2 + rowbase;
#pragma unroll
        for (int i4 = 0; i4 < 4; i4++) {
            float4 v = *(const float4*)(p + i4 * 4);
            yv[i4 * 4 + 0] += v.x;
            yv[i4 * 4 + 1] += v.y;
            yv[i4 * 4 + 2] += v.z;
            yv[i4 * 4 + 3] += v.w;
        }
    }
#pragma unroll
    for (int i = 0; i < 16; i++) {
        int oc = hh * 64 + cq + i;
        float inv = g1[oc] / sqrtf(v1[oc] + 1e-5f);
        yv[i] = (yv[i] - m1[oc]) * inv + b1[oc];
    }

    size_t reg = (size_t)(tb * NHEAD + hh) * 4096;
    if (cq < 32) {
#pragma unroll
        for (int gi = 0; gi < 2; gi++) {
            int c0 = cq + gi * 8;
            f16x8 h, l;
#pragma unroll
            for (int j = 0; j < 8; j++) {
                float v = yv[gi * 8 + j];
                _Float16 hi = (_Float16)v;
                h[j] = hi;
                l[j] = (_Float16)((v - (float)hi) * 2048.0f);
            }
            size_t a = reg + (size_t)(((pp >> 4) * 4 + (c0 >> 3)) * 128 + (pp & 15) * 8);
            *(f16x8*)(A1 + a) = h;
            *(f16x8*)(A1 + a + 2048) = l;
        }
    } else {
#pragma unroll
        for (int i = 0; i < 16; i++) y2ls[cq - 32 + i][pp] = yv[i];
    }
    __syncthreads();
    int d16 = tid & 15, grp = tid >> 4;
    f16x8 h, l;
#pragma unroll
    for (int j = 0; j < 8; j++) {
        float v = y2ls[(grp >> 3) * 16 + d16][((grp >> 2) & 1) * 32 + (grp & 3) * 8 + j];
        _Float16 hi = (_Float16)v;
        h[j] = hi;
        l[j] = (_Float16)((v - (float)hi) * 2048.0f);
    }
    size_t a = reg + (size_t)((grp * 16 + d16) * 8);
    *(f16x8*)(A2 + a) = h;
    *(f16x8*)(A2 + a + 2048) = l;
}

// ---------------- K3: fused attention via MFMA -> OsF ----------------
__global__ __launch_bounds__(256) void k_attn_mfma(const _Float16* __restrict__ xsF,
                                                   const _Float16* __restrict__ A1,
                                                   const _Float16* __restrict__ A2,
                                                   const float* __restrict__ fr_x,
                                                   const float* __restrict__ fr_attn,
                                                   _Float16* __restrict__ OsF) {
    __shared__ __align__(16) _Float16 Bs[4][128][8];    // 8 KB xr tile
    __shared__ __align__(16) _Float16 Sat[8][128][8];   // 16 KB attn spikes

    int nt = blockIdx.x;
    int bh = blockIdx.y;
    int b = bh / NHEAD, hh = bh % NHEAD;
    int tid = threadIdx.x;
    int w = tid >> 6;
    int lane = tid & 63;
    int l16 = lane & 15, lq = lane >> 4;

    float scale1 = 1.0f / sqrtf(fr_x[hh] * 32.0f);
    float scale2 = 1.0f / sqrtf(fr_attn[hh] * 64.0f);

    float va[8][4];
    float vo[2][2][4];
#pragma unroll
    for (int nf = 0; nf < 8; nf++)
#pragma unroll
        for (int r = 0; r < 4; r++) va[nf][r] = 0.0f;
#pragma unroll
    for (int dt = 0; dt < 2; dt++)
#pragma unroll
        for (int nf = 0; nf < 2; nf++)
#pragma unroll
            for (int r = 0; r < 4; r++) vo[dt][nf][r] = 0.0f;

    for (int t = 0; t < TT; t++) {
        int tb = t * BB + b;
        size_t reg = (size_t)(tb * NHEAD + hh);
        const char* src = (const char*)(xsF + (reg * 8 + nt) * 4096);
#if USE_GLL
        load_lds16(src + tid * 16, (char*)&Bs[0][0][0] + tid * 16);
        load_lds16(src + tid * 16 + 4096, (char*)&Bs[0][0][0] + tid * 16 + 4096);
#else
        *(float4*)((char*)&Bs[0][0][0] + tid * 16) = *(const float4*)(src + tid * 16);
        *(float4*)((char*)&Bs[0][0][0] + tid * 16 + 4096) = *(const float4*)(src + tid * 16 + 4096);
#endif
        const _Float16* a1b = A1 + reg * 4096;
        f16x8 a1h = *(const f16x8*)(a1b + (size_t)(((w * 4 + lq) * 16 + l16) * 8));
        f16x8 a1l = *(const f16x8*)(a1b + 2048 + (size_t)(((w * 4 + lq) * 16 + l16) * 8));
        __syncthreads();

        f32x4 ah[8], al[8];
#pragma unroll
        for (int nf = 0; nf < 8; nf++) {
            ah[nf] = (f32x4){0.f, 0.f, 0.f, 0.f};
            al[nf] = (f32x4){0.f, 0.f, 0.f, 0.f};
        }
#pragma unroll
        for (int nf = 0; nf < 8; nf++) {
            f16x8 bf = *(const f16x8*)&Bs[lq][nf * 16 + l16][0];
            ah[nf] = __builtin_amdgcn_mfma_f32_16x16x32_f16(a1h, bf, ah[nf], 0, 0, 0);
            al[nf] = __builtin_amdgcn_mfma_f32_16x16x32_f16(a1l, bf, al[nf], 0, 0, 0);
        }
        int pq = w * 2 + (lq >> 1);
#pragma unroll
        for (int nf = 0; nf < 8; nf++) {
            f16x4 sp;
#pragma unroll
            for (int r = 0; r < 4; r++) {
                float a = (ah[nf][r] + al[nf][r] * (1.0f / 2048.0f)) * scale1;
                float v = va[nf][r];
                v += (a - v) * 0.5f;
                float s = (v >= 1.0f) ? 1.0f : 0.0f;
                va[nf][r] = (s > 0.0f) ? 0.0f : v;
                sp[r] = (_Float16)s;
            }
            *(f16x4*)&Sat[pq][nf * 16 + l16][(lq & 1) * 4] = sp;
        }
        __syncthreads();

        const _Float16* a2b = A2 + reg * 4096;
        f32x4 oh[2][2], ol[2][2];
#pragma unroll
        for (int dt = 0; dt < 2; dt++)
#pragma unroll
            for (int nf = 0; nf < 2; nf++) {
                oh[dt][nf] = (f32x4){0.f, 0.f, 0.f, 0.f};
                ol[dt][nf] = (f32x4){0.f, 0.f, 0.f, 0.f};
            }
#pragma unroll
        for (int ks = 0; ks < 2; ks++) {
            f16x8 bf0 = *(const f16x8*)&Sat[ks * 4 + lq][w * 32 + l16][0];
            f16x8 bf1 = *(const f16x8*)&Sat[ks * 4 + lq][w * 32 + 16 + l16][0];
#pragma unroll
            for (int dt = 0; dt < 2; dt++) {
                size_t ao = (size_t)(((dt * 8 + ks * 4 + lq) * 16 + l16) * 8);
                f16x8 a2h = *(const f16x8*)(a2b + ao);
                f16x8 a2l = *(const f16x8*)(a2b + 2048 + ao);
                oh[dt][0] = __builtin_amdgcn_mfma_f32_16x16x32_f16(a2h, bf0, oh[dt][0], 0, 0, 0);
                ol[dt][0] = __builtin_amdgcn_mfma_f32_16x16x32_f16(a2l, bf0, ol[dt][0], 0, 0, 0);
                oh[dt][1] = __builtin_amdgcn_mfma_f32_16x16x32_f16(a2h, bf1, oh[dt][1], 0, 0, 0);
                ol[dt][1] = __builtin_amdgcn_mfma_f32_16x16x32_f16(a2l, bf1, ol[dt][1], 0, 0, 0);
            }
        }
        _Float16* og = OsF + (reg * 8 + nt) * 4096;
#pragma unroll
        for (int dt = 0; dt < 2; dt++)
#pragma unroll
            for (int nf = 0; nf < 2; nf++) {
                f16x4 sp;
#pragma unroll
                for (int r = 0; r < 4; r++) {
                    float a = (oh[dt][nf][r] + ol[dt][nf][r] * (1.0f / 2048.0f)) * scale2;
                    float v = vo[dt][nf][r];
                    v += (a - v) * 0.5f;
                    float s = (v >= 1.0f) ? 1.0f : 0.0f;
                    vo[dt][nf][r] = (s > 0.0f) ? 0.0f : v;
                    sp[r] = (_Float16)s;
                }
                int n = w * 32 + nf * 16 + l16;
                *(f16x4*)(og + (size_t)((dt * 2 + (lq >> 1)) * 1024 + n * 8 + (lq & 1) * 4)) = sp;
            }
        __syncthreads();
    }
}

// ---------------- K4: projection GEMM via MFMA + BN2 + residual -> d_out ----------------
__global__ __launch_bounds__(256) void k_proj_mfma(const _Float16* __restrict__ OsF,
                                                   const _Float16* __restrict__ WpH,
                                                   const float* __restrict__ g2,
                                                   const float* __restrict__ b2,
                                                   const float* __restrict__ m2,
                                                   const float* __restrict__ vv2,
                                                   const float* __restrict__ x,
                                                   float* __restrict__ out) {
    __shared__ __align__(16) _Float16 Bs[4][128][8];

    int nt = blockIdx.x;
    int ot = blockIdx.y;
    int tb = blockIdx.z;
    int tid = threadIdx.x;
    int wave = tid >> 6;
    int lane = tid & 63;
    int l16 = lane & 15, lq = lane >> 4;
    int wr = (wave & 1) * 64, wc = (wave >> 1) * 64;

    f32x4 acc[4][4];
#pragma unroll
    for (int i = 0; i < 4; i++)
#pragma unroll
        for (int j = 0; j < 4; j++) acc[i][j] = (f32x4){0.f, 0.f, 0.f, 0.f};

    for (int kb = 0; kb < 12; ++kb) {
        __syncthreads();
        const char* src = (const char*)(OsF + ((size_t)(tb * NHEAD + kb) * 8 + nt) * 4096);
#if USE_GLL
#pragma unroll
        for (int i = 0; i < 2; ++i) {
            int off = (tid + i * 256) * 16;
            load_lds16(src + off, (char*)&Bs[0][0][0] + off);
        }
#else
#pragma unroll
        for (int i = 0; i < 2; ++i) {
            int off = (tid + i * 256) * 16;
            *(float4*)((char*)&Bs[0][0][0] + off) = *(const float4*)(src + off);
        }
#endif
        const _Float16* wbase = WpH + (size_t)(kb * 3 + ot) * 4096 + lq * 1024;
        f16x8 af[4];
#pragma unroll
        for (int fi = 0; fi < 4; fi++)
            af[fi] = *(const f16x8*)(wbase + (size_t)(wr + fi * 16 + l16) * 8);
        __syncthreads();

        f16x8 bf[4];
#pragma unroll
        for (int fj = 0; fj < 4; fj++)
            bf[fj] = *(const f16x8*)&Bs[lq][wc + fj * 16 + l16][0];
#pragma unroll
        for (int fi = 0; fi < 4; fi++)
#pragma unroll
            for (int fj = 0; fj < 4; fj++)
                acc[fi][fj] = __builtin_amdgcn_mfma_f32_16x16x32_f16(af[fi], bf[fj], acc[fi][fj], 0, 0, 0);
    }

    size_t orow_base = (size_t)tb * CC * HWN;
    int n_base = nt * 128 + wc;
#pragma unroll
    for (int fi = 0; fi < 4; fi++) {
        float invv[4], muv[4], btv[4];
#pragma unroll
        for (int r = 0; r < 4; r++) {
            int o = ot * 128 + wr + fi * 16 + lq * 4 + r;
            invv[r] = g2[o] / sqrtf(vv2[o] + 1e-5f);
            muv[r] = m2[o];
            btv[r] = b2[o];
        }
#pragma unroll
        for (int fj = 0; fj < 4; fj++) {
#pragma unroll
            for (int r = 0; r < 4; r++) {
                int o = ot * 128 + wr + fi * 16 + lq * 4 + r;
                size_t addr = orow_base + (size_t)o * HWN + n_base + fj * 16 + l16;
                out[addr] = (acc[fi][fj][r] - muv[r]) * invv[r] + btv[r] + x[addr];
            }
        }
    }
}

extern "C" void kernel_launch(void* const* d_in, const int* in_sizes, int n_in,
                              void* d_out, int out_size, void* d_ws, size_t ws_size,
                              hipStream_t stream) {
    const float* x = (const float*)d_in[0];
    const float* w_conv = (const float*)d_in[1];
    const float* bn1_gamma = (const float*)d_in[2];
    const float* bn1_beta = (const float*)d_in[3];
    const float* bn1_mean = (const float*)d_in[4];
    const float* bn1_var = (const float*)d_in[5];
    const float* w_proj = (const float*)d_in[6];
    const float* bn2_gamma = (const float*)d_in[7];
    const float* bn2_beta = (const float*)d_in[8];
    const float* bn2_mean = (const float*)d_in[9];
    const float* bn2_var = (const float*)d_in[10];
    const float* fr_x = (const float*)d_in[11];
    const float* fr_attn = (const float*)d_in[12];

    // workspace layout
    const size_t FRAG = (size_t)16 * 192 * 4096 * 2;              // 25,165,824 (xsC; also xsF/OsF size)
    const size_t AB = (size_t)TT * BB * NHEAD * 4096 * 2;         // 3,145,728 (A1 / A2)
    const size_t WB = (size_t)KCONV * C2 * 2;                     // 9,437,184
    const size_t WPB = (size_t)CC * CC * 2;                       // 294,912
    const size_t PB = (size_t)MROWS * C2 * 4;                     // 6,291,456 per split
    _Float16* xsC = (_Float16*)d_ws;
    _Float16* xsF = (_Float16*)((char*)xsC + FRAG);
    _Float16* OsF = (_Float16*)((char*)xsF + FRAG);
    _Float16* A1 = (_Float16*)((char*)OsF + FRAG);
    _Float16* A2 = (_Float16*)((char*)A1 + AB);
    _Float16* W0 = (_Float16*)((char*)A2 + AB);
    _Float16* W1 = (_Float16*)((char*)W0 + WB);
    _Float16* WpH = (_Float16*)((char*)W1 + WB);
    char* tail = (char*)WpH + WPB;

    int KS;
    float* P;
    if (ws_size >= (size_t)(tail - (char*)d_ws) + 8 * PB) {
        KS = 8;
        P = (float*)tail;
    } else if (ws_size >= (size_t)(tail - (char*)d_ws) + 4 * PB) {
        KS = 4;
        P = (float*)tail;
    } else {
        KS = 2;                    // alias P onto OsF region (OsF written later by k_attn)
        P = (float*)OsF;
    }
    int kbPerSplit = KB_TOT / KS;

    k_pack<<<(KCONV * C2 / 8) / 256, 256, 0, stream>>>(w_conv, W0, W1);
    k_pack_wp<<<(CC * CC / 8) / 256, 256, 0, stream>>>(w_proj, WpH);
    k_lif1<<<dim3(16, BB * NHEAD), 256, 0, stream>>>(x, xsC, xsF);
    k_conv_mfma<<<dim3(16, 6, KS), 256, 0, stream>>>(xsC, W0, W1, P, kbPerSplit);
    k_reduce_frag<<<32 * NHEAD, 256, 0, stream>>>(P, bn1_gamma, bn1_beta, bn1_mean, bn1_var, A1, A2, KS);
    k_attn_mfma<<<dim3(8, BB * NHEAD), 256, 0, stream>>>(xsF, A1, A2, fr_x, fr_attn, OsF);
    k_proj_mfma<<<dim3(8, 3, 32), 256, 0, stream>>>(OsF, WpH, bn2_gamma, bn2_beta, bn2_mean, bn2_var, x, (float*)d_out);
}